// Round 1
// baseline (619.494 us; speedup 1.0000x reference)
//
#include <hip/hip_runtime.h>
#include <math.h>

constexpr int Bb = 8;
constexpr int Nn = 9216;   // 96*96
constexpr int Cc = 256;    // = D
constexpr int Oo = 512;    // 2C
constexpr float LN_EPS = 1e-5f;
constexpr int KSPLIT = 9;  // context GEMM split-K chunks (9216 = 9*1024)

// ---------------- K1: LayerNorm (wave per row). which=1 (x2) also emits row softmax stats.
__global__ __launch_bounds__(256) void k_ln(const float* __restrict__ x1,
                                            const float* __restrict__ x2,
                                            const float* __restrict__ nw,
                                            const float* __restrict__ nb,
                                            float* __restrict__ n1,
                                            float* __restrict__ n2,
                                            float* __restrict__ rowm,
                                            float* __restrict__ rowsum) {
    const int lane = threadIdx.x & 63;
    const long long row = (long long)blockIdx.x * 4 + (threadIdx.x >> 6);
    const int which = blockIdx.y;
    const float* x = which ? x2 : x1;
    float* op = which ? n2 : n1;

    const float4 v = reinterpret_cast<const float4*>(x)[row * 64 + lane];
    float s = v.x + v.y + v.z + v.w;
    float q = v.x * v.x + v.y * v.y + v.z * v.z + v.w * v.w;
#pragma unroll
    for (int m = 32; m; m >>= 1) { s += __shfl_xor(s, m); q += __shfl_xor(q, m); }
    const float mu = s * (1.0f / Cc);
    const float rstd = rsqrtf(q * (1.0f / Cc) - mu * mu + LN_EPS);

    const float4 w4 = reinterpret_cast<const float4*>(nw)[lane];
    const float4 b4 = reinterpret_cast<const float4*>(nb)[lane];
    float4 y;
    y.x = (v.x - mu) * rstd * w4.x + b4.x;
    y.y = (v.y - mu) * rstd * w4.y + b4.y;
    y.z = (v.z - mu) * rstd * w4.z + b4.z;
    y.w = (v.w - mu) * rstd * w4.w + b4.w;
    reinterpret_cast<float4*>(op)[row * 64 + lane] = y;

    if (which) {
        float mx = fmaxf(fmaxf(y.x, y.y), fmaxf(y.z, y.w));
#pragma unroll
        for (int m = 32; m; m >>= 1) mx = fmaxf(mx, __shfl_xor(mx, m));
        float es = __expf(y.x - mx) + __expf(y.y - mx) + __expf(y.z - mx) + __expf(y.w - mx);
#pragma unroll
        for (int m = 32; m; m >>= 1) es += __shfl_xor(es, m);
        if (lane == 0) { rowm[row] = mx; rowsum[row] = es; }
    }
}

// ---------------- K2a: per-(b,d) online softmax stats over n, partial per 256-row chunk
__global__ __launch_bounds__(256) void k_colstat_part(const float* __restrict__ n2,
                                                      float* __restrict__ pM,
                                                      float* __restrict__ pS) {
    const int d = threadIdx.x, ch = blockIdx.x, b = blockIdx.y;
    const float* base = n2 + ((long long)b * Nn + (long long)ch * 256) * Cc + d;
    float m = -INFINITY, s = 0.0f;
    for (int r = 0; r < 256; ++r) {
        const float x = base[(long long)r * Cc];
        const float nm = fmaxf(m, x);
        s = s * __expf(m - nm) + __expf(x - nm);
        m = nm;
    }
    pM[(b * 36 + ch) * Cc + d] = m;
    pS[(b * 36 + ch) * Cc + d] = s;
}

// ---------------- K2b: combine 36 chunk partials
__global__ __launch_bounds__(256) void k_colstat_comb(const float* __restrict__ pM,
                                                      const float* __restrict__ pS,
                                                      float* __restrict__ colM,
                                                      float* __restrict__ colS) {
    const int d = threadIdx.x, b = blockIdx.x;
    float m = -INFINITY, s = 0.0f;
    for (int ch = 0; ch < 36; ++ch) {
        const float cm = pM[(b * 36 + ch) * Cc + d];
        const float cs = pS[(b * 36 + ch) * Cc + d];
        const float nm = fmaxf(m, cm);
        s = s * __expf(m - nm) + cs * __expf(cm - nm);
        m = nm;
    }
    colM[b * Cc + d] = m;
    colS[b * Cc + d] = s;
}

// ---------------- K3: context partials: ctxp[kc][b][d][e] = sum_{n in chunk} keyv[d,n]*n1[n,e]
// grid (16, KSPLIT, 8), block 256. 64x64 tile, K-chunk = 1024.
__global__ __launch_bounds__(256) void k_ctx(const float* __restrict__ n2,
                                             const float* __restrict__ n1,
                                             const float* __restrict__ colM,
                                             const float* __restrict__ colS,
                                             float* __restrict__ ctxp) {
    __shared__ float As[16][64], Bs[16][64];
    __shared__ float Md[64], iS[64];
    const int b = blockIdx.z, kc = blockIdx.y;
    const int d0 = (blockIdx.x >> 2) * 64, e0 = (blockIdx.x & 3) * 64;
    const int t = threadIdx.x, tx = t & 15, ty = t >> 4;
    if (t < 64) { Md[t] = colM[b * Cc + d0 + t]; iS[t] = 1.0f / colS[b * Cc + d0 + t]; }
    const int s_kk = t >> 4, s_d4 = (t & 15) * 4;
    float acc[4][4] = {{0.f}};
    __syncthreads();
    for (int it = 0; it < 64; ++it) {
        const long long nrow = (long long)b * Nn + kc * 1024 + it * 16 + s_kk;
        const float4 xa = *reinterpret_cast<const float4*>(n2 + nrow * Cc + d0 + s_d4);
        const float4 xb = *reinterpret_cast<const float4*>(n1 + nrow * Cc + e0 + s_d4);
        float4 ea;
        ea.x = __expf(xa.x - Md[s_d4 + 0]) * iS[s_d4 + 0];
        ea.y = __expf(xa.y - Md[s_d4 + 1]) * iS[s_d4 + 1];
        ea.z = __expf(xa.z - Md[s_d4 + 2]) * iS[s_d4 + 2];
        ea.w = __expf(xa.w - Md[s_d4 + 3]) * iS[s_d4 + 3];
        __syncthreads();
        *reinterpret_cast<float4*>(&As[s_kk][s_d4]) = ea;
        *reinterpret_cast<float4*>(&Bs[s_kk][s_d4]) = xb;
        __syncthreads();
#pragma unroll
        for (int kk = 0; kk < 16; ++kk) {
            const float4 a4 = *reinterpret_cast<const float4*>(&As[kk][ty * 4]);
            const float4 b4 = *reinterpret_cast<const float4*>(&Bs[kk][tx * 4]);
            const float aa[4] = {a4.x, a4.y, a4.z, a4.w};
            const float bb[4] = {b4.x, b4.y, b4.z, b4.w};
#pragma unroll
            for (int i = 0; i < 4; ++i)
#pragma unroll
                for (int j = 0; j < 4; ++j) acc[i][j] = fmaf(aa[i], bb[j], acc[i][j]);
        }
    }
#pragma unroll
    for (int i = 0; i < 4; ++i) {
        const float4 v = make_float4(acc[i][0], acc[i][1], acc[i][2], acc[i][3]);
        *reinterpret_cast<float4*>(ctxp + (((long long)kc * Bb + b) * Cc + d0 + ty * 4 + i) * Cc + e0 + tx * 4) = v;
    }
}

// ---------------- K3b: deterministic split-K reduction
__global__ __launch_bounds__(256) void k_ctxred(const float* __restrict__ ctxp,
                                                float* __restrict__ ctx) {
    const long long i4 = ((long long)blockIdx.x * 256 + threadIdx.x) * 4;
    float4 s = make_float4(0.f, 0.f, 0.f, 0.f);
    for (int kc = 0; kc < KSPLIT; ++kc) {
        const float4 v = *reinterpret_cast<const float4*>(ctxp + (long long)kc * (Bb * Cc * Cc) + i4);
        s.x += v.x; s.y += v.y; s.z += v.z; s.w += v.w;
    }
    *reinterpret_cast<float4*>(ctx + i4) = s;
}

// ---------------- K4: rank + combined top-k softmax coefficients. block per (b,d) row.
__global__ __launch_bounds__(256) void k_rank(const float* __restrict__ ctx,
                                              const float* __restrict__ aw,
                                              float* __restrict__ Ac) {
    __shared__ float row[256];
    __shared__ float red[256];
    const int d = blockIdx.x, b = blockIdx.y, e = threadIdx.x;
    const float c = ctx[((long long)(b * Cc + d)) * Cc + e];
    row[e] = c;
    __syncthreads();
    int p = 0;
    for (int j = 0; j < 256; ++j) {
        const float cj = row[j];
        p += (cj > c) || (cj == c && j < e);  // stable top_k rank (0-based)
    }
    // row max
    red[e] = c; __syncthreads();
    for (int s_ = 128; s_; s_ >>= 1) { if (e < s_) red[e] = fmaxf(red[e], red[e + s_]); __syncthreads(); }
    const float m = red[0];
    const float ex = __expf(c - m);
    const int kks[4] = {128, 170, 192, 204};  // D/2, 2D/3, 3D/4, 4D/5 for D=256
    float Zv[4];
#pragma unroll
    for (int i = 0; i < 4; ++i) {
        __syncthreads();
        red[e] = (p < kks[i]) ? ex : 0.0f;
        __syncthreads();
        for (int s_ = 128; s_; s_ >>= 1) { if (e < s_) red[e] += red[e + s_]; __syncthreads(); }
        Zv[i] = red[0];
    }
    float wsum = 0.0f;
#pragma unroll
    for (int i = 0; i < 4; ++i)
        if (p < kks[i]) wsum += aw[i] / Zv[i];
    Ac[((long long)(b * Cc + d)) * Cc + e] = ex * wsum;
}

// ---------------- K5: WA[b,o,e] = sum_d W[o,d] * A[b,d,e].  grid (32, 8), block 256.
__global__ __launch_bounds__(256) void k_wa(const float* __restrict__ W,
                                            const float* __restrict__ Ac,
                                            float* __restrict__ WAb) {
    __shared__ float As[16][64], Bs[16][64];
    const int b = blockIdx.y;
    const int o0 = (blockIdx.x >> 2) * 64, e0 = (blockIdx.x & 3) * 64;
    const int t = threadIdx.x, tx = t & 15, ty = t >> 4;
    const int a_oo = t >> 2, a_k4 = (t & 3) * 4;
    const int b_kk = t >> 4, b_e4 = (t & 15) * 4;
    float acc[4][4] = {{0.f}};
    for (int kd = 0; kd < 256; kd += 16) {
        const float4 wv = *reinterpret_cast<const float4*>(W + (o0 + a_oo) * Cc + kd + a_k4);
        const float4 av = *reinterpret_cast<const float4*>(Ac + ((long long)(b * Cc + kd + b_kk)) * Cc + e0 + b_e4);
        __syncthreads();
        As[a_k4 + 0][a_oo] = wv.x; As[a_k4 + 1][a_oo] = wv.y;
        As[a_k4 + 2][a_oo] = wv.z; As[a_k4 + 3][a_oo] = wv.w;
        *reinterpret_cast<float4*>(&Bs[b_kk][b_e4]) = av;
        __syncthreads();
#pragma unroll
        for (int kk = 0; kk < 16; ++kk) {
            const float4 a4 = *reinterpret_cast<const float4*>(&As[kk][ty * 4]);
            const float4 b4 = *reinterpret_cast<const float4*>(&Bs[kk][tx * 4]);
            const float aa[4] = {a4.x, a4.y, a4.z, a4.w};
            const float bb[4] = {b4.x, b4.y, b4.z, b4.w};
#pragma unroll
            for (int i = 0; i < 4; ++i)
#pragma unroll
                for (int j = 0; j < 4; ++j) acc[i][j] = fmaf(aa[i], bb[j], acc[i][j]);
        }
    }
#pragma unroll
    for (int i = 0; i < 4; ++i) {
        const float4 v = make_float4(acc[i][0], acc[i][1], acc[i][2], acc[i][3]);
        *reinterpret_cast<float4*>(WAb + ((long long)(b * Oo + o0 + ty * 4 + i)) * Cc + e0 + tx * 4) = v;
    }
}

// ---------------- K6: rp[b,n,o] = sum_e WA[b,o,e]*query[b,e,n] + rb[o]. grid (144, 8, 8).
__global__ __launch_bounds__(256) void k_rp(const float* __restrict__ WAb,
                                            const float* __restrict__ n2,
                                            const float* __restrict__ rowm,
                                            const float* __restrict__ rowsum,
                                            const float* __restrict__ rbias,
                                            float* __restrict__ rp) {
    __shared__ float As[16][64], Bs[16][64];
    __shared__ float rm[64], ri[64];
    const int b = blockIdx.z, o0 = blockIdx.y * 64, n0 = blockIdx.x * 64;
    const int t = threadIdx.x, tx = t & 15, ty = t >> 4;
    if (t < 64) { rm[t] = rowm[b * Nn + n0 + t]; ri[t] = 1.0f / rowsum[b * Nn + n0 + t]; }
    const int a_oo = t >> 2, a_k4 = (t & 3) * 4;
    const int b_nn = t >> 2, b_k4 = (t & 3) * 4;
    float acc[4][4] = {{0.f}};
    __syncthreads();
    for (int kd = 0; kd < 256; kd += 16) {
        const float4 wv = *reinterpret_cast<const float4*>(WAb + ((long long)(b * Oo + o0 + a_oo)) * Cc + kd + a_k4);
        const float4 qv = *reinterpret_cast<const float4*>(n2 + ((long long)b * Nn + n0 + b_nn) * Cc + kd + b_k4);
        const float m_ = rm[b_nn], s_ = ri[b_nn];
        float4 ev;
        ev.x = __expf(qv.x - m_) * s_;
        ev.y = __expf(qv.y - m_) * s_;
        ev.z = __expf(qv.z - m_) * s_;
        ev.w = __expf(qv.w - m_) * s_;
        __syncthreads();
        As[a_k4 + 0][a_oo] = wv.x; As[a_k4 + 1][a_oo] = wv.y;
        As[a_k4 + 2][a_oo] = wv.z; As[a_k4 + 3][a_oo] = wv.w;
        Bs[b_k4 + 0][b_nn] = ev.x; Bs[b_k4 + 1][b_nn] = ev.y;
        Bs[b_k4 + 2][b_nn] = ev.z; Bs[b_k4 + 3][b_nn] = ev.w;
        __syncthreads();
#pragma unroll
        for (int kk = 0; kk < 16; ++kk) {
            const float4 a4 = *reinterpret_cast<const float4*>(&As[kk][ty * 4]);
            const float4 b4 = *reinterpret_cast<const float4*>(&Bs[kk][tx * 4]);
            const float aa[4] = {a4.x, a4.y, a4.z, a4.w};
            const float bb[4] = {b4.x, b4.y, b4.z, b4.w};
#pragma unroll
            for (int i = 0; i < 4; ++i)
#pragma unroll
                for (int j = 0; j < 4; ++j) acc[i][j] = fmaf(aa[i], bb[j], acc[i][j]);
        }
    }
#pragma unroll
    for (int j = 0; j < 4; ++j) {
        const int n = n0 + tx * 4 + j;
        float4 v;
        v.x = acc[0][j] + rbias[o0 + ty * 4 + 0];
        v.y = acc[1][j] + rbias[o0 + ty * 4 + 1];
        v.z = acc[2][j] + rbias[o0 + ty * 4 + 2];
        v.w = acc[3][j] + rbias[o0 + ty * 4 + 3];
        *reinterpret_cast<float4*>(rp + ((long long)b * Nn + n) * Oo + o0 + ty * 4) = v;
    }
}

// ---------------- K7: LayerNorm over O=512 + transposed write out[b,o,n]. grid (576, 8).
__global__ __launch_bounds__(256) void k_ln2t(const float* __restrict__ rp,
                                              const float* __restrict__ nw,
                                              const float* __restrict__ nb,
                                              float* __restrict__ out) {
    __shared__ float tile[16][520];
    __shared__ float psum[16][16], psq[16][16];
    __shared__ float mu[16], rs[16];
    const int b = blockIdx.y, n0 = blockIdx.x * 16, t = threadIdx.x;
#pragma unroll
    for (int i = 0; i < 8; ++i) {
        const int idx = i * 256 + t;       // float4 index, 0..2047
        const int r = idx >> 7;            // 128 float4 per 512-row
        const int o4 = (idx & 127) * 4;
        const float4 v = *reinterpret_cast<const float4*>(rp + ((long long)b * Nn + n0 + r) * Oo + o4);
        *reinterpret_cast<float4*>(&tile[r][o4]) = v;
    }
    __syncthreads();
    {
        const int r = t >> 4, sub = t & 15;
        float s = 0.f, q = 0.f;
#pragma unroll
        for (int i = 0; i < 32; ++i) { const float v = tile[r][sub + 16 * i]; s += v; q += v * v; }
        psum[r][sub] = s; psq[r][sub] = q;
    }
    __syncthreads();
    if (t < 16) {
        float s = 0.f, q = 0.f;
        for (int i = 0; i < 16; ++i) { s += psum[t][i]; q += psq[t][i]; }
        const float m = s * (1.0f / Oo);
        mu[t] = m;
        rs[t] = rsqrtf(q * (1.0f / Oo) - m * m + LN_EPS);
    }
    __syncthreads();
#pragma unroll
    for (int i = 0; i < 8; ++i) {
        const int o = (t >> 2) + 64 * i;
        const int rb_ = (t & 3) * 4;
        const float w = nw[o], bbv = nb[o];
        float4 v;
        v.x = (tile[rb_ + 0][o] - mu[rb_ + 0]) * rs[rb_ + 0] * w + bbv;
        v.y = (tile[rb_ + 1][o] - mu[rb_ + 1]) * rs[rb_ + 1] * w + bbv;
        v.z = (tile[rb_ + 2][o] - mu[rb_ + 2]) * rs[rb_ + 2] * w + bbv;
        v.w = (tile[rb_ + 3][o] - mu[rb_ + 3]) * rs[rb_ + 3] * w + bbv;
        *reinterpret_cast<float4*>(out + ((long long)(b * Oo + o)) * Nn + n0 + rb_) = v;
    }
}

extern "C" void kernel_launch(void* const* d_in, const int* in_sizes, int n_in,
                              void* d_out, int out_size, void* d_ws, size_t ws_size,
                              hipStream_t stream) {
    (void)in_sizes; (void)n_in; (void)out_size; (void)ws_size;
    const float* x1    = (const float*)d_in[0];
    const float* x2    = (const float*)d_in[1];
    const float* n1w   = (const float*)d_in[2];
    const float* n1b   = (const float*)d_in[3];
    const float* rw    = (const float*)d_in[4];
    const float* rbias = (const float*)d_in[5];
    const float* n2w   = (const float*)d_in[6];
    const float* n2b   = (const float*)d_in[7];
    const float* aw    = (const float*)d_in[8];
    float* out = (float*)d_out;

    // d_out doubles as scratch for n1/n2 (dead before the final overwrite)
    float* n1 = out;
    float* n2 = out + (size_t)Bb * Nn * Cc;

    float* ws = (float*)d_ws;
    size_t off = 0;
    float* rp     = ws + off; off += (size_t)Bb * Nn * Oo;            // 37,748,736
    float* ctxp   = ws + off; off += (size_t)KSPLIT * Bb * Cc * Cc;   //  4,718,592
    float* ctx    = ws + off; off += (size_t)Bb * Cc * Cc;            //    524,288
    float* Ac     = ws + off; off += (size_t)Bb * Cc * Cc;            //    524,288
    float* WAb    = ws + off; off += (size_t)Bb * Oo * Cc;            //  1,048,576
    float* rowm   = ws + off; off += (size_t)Bb * Nn;
    float* rowsum = ws + off; off += (size_t)Bb * Nn;
    float* pM     = ws + off; off += (size_t)Bb * 36 * Cc;
    float* pS     = ws + off; off += (size_t)Bb * 36 * Cc;
    float* colM   = ws + off; off += (size_t)Bb * Cc;
    float* colS   = ws + off; off += (size_t)Bb * Cc;

    k_ln<<<dim3(Bb * Nn / 4, 2), 256, 0, stream>>>(x1, x2, n1w, n1b, n1, n2, rowm, rowsum);
    k_colstat_part<<<dim3(36, Bb), 256, 0, stream>>>(n2, pM, pS);
    k_colstat_comb<<<dim3(Bb), 256, 0, stream>>>(pM, pS, colM, colS);
    k_ctx<<<dim3(16, KSPLIT, Bb), 256, 0, stream>>>(n2, n1, colM, colS, ctxp);
    k_ctxred<<<dim3(512), 256, 0, stream>>>(ctxp, ctx);
    k_rank<<<dim3(Cc, Bb), 256, 0, stream>>>(ctx, aw, Ac);
    k_wa<<<dim3(32, Bb), 256, 0, stream>>>(rw, Ac, WAb);
    k_rp<<<dim3(144, 8, Bb), 256, 0, stream>>>(WAb, n2, rowm, rowsum, rbias, rp);
    k_ln2t<<<dim3(576, Bb), 256, 0, stream>>>(rp, n2w, n2b, out);
}

// Round 2
// 491.436 us; speedup vs baseline: 1.2606x; 1.2606x over previous
//
#include <hip/hip_runtime.h>
#include <math.h>

typedef __attribute__((ext_vector_type(8))) short short8;
typedef __attribute__((ext_vector_type(4))) float f32x4;
typedef unsigned short u16;

constexpr int Bb = 8;
constexpr int Nn = 9216;   // 96*96
constexpr int Cc = 256;    // = D
constexpr int Oo = 512;    // 2C
constexpr float LN_EPS = 1e-5f;
constexpr int KSPLIT = 9;  // context GEMM split-K chunks (9216 = 9*1024)

static __device__ __forceinline__ u16 f2bf(float f) {
    unsigned u = __builtin_bit_cast(unsigned, f);
    u += 0x7fffu + ((u >> 16) & 1u);   // RNE
    return (u16)(u >> 16);
}

// ---------------- K0: per-row mean/rstd of x1 (LN stats only; normalize happens in k_ctx)
__global__ __launch_bounds__(256) void k_stat1(const float* __restrict__ x1,
                                               float* __restrict__ x1mu,
                                               float* __restrict__ x1rs) {
    const int lane = threadIdx.x & 63;
    const long long row = (long long)blockIdx.x * 4 + (threadIdx.x >> 6);
    const float4 v = reinterpret_cast<const float4*>(x1)[row * 64 + lane];
    float s = v.x + v.y + v.z + v.w;
    float q = v.x * v.x + v.y * v.y + v.z * v.z + v.w * v.w;
#pragma unroll
    for (int m = 32; m; m >>= 1) { s += __shfl_xor(s, m); q += __shfl_xor(q, m); }
    const float mu = s * (1.0f / Cc);
    const float rstd = rsqrtf(q * (1.0f / Cc) - mu * mu + LN_EPS);
    if (lane == 0) { x1mu[row] = mu; x1rs[row] = rstd; }
}

// ---------------- K1: LayerNorm of x2 -> n2 (f32) + row-softmax exp -> Qexp (bf16)
__global__ __launch_bounds__(256) void k_ln(const float* __restrict__ x2,
                                            const float* __restrict__ nw,
                                            const float* __restrict__ nb,
                                            float* __restrict__ n2,
                                            u16* __restrict__ Qexp) {
    const int lane = threadIdx.x & 63;
    const long long row = (long long)blockIdx.x * 4 + (threadIdx.x >> 6);

    const float4 v = reinterpret_cast<const float4*>(x2)[row * 64 + lane];
    float s = v.x + v.y + v.z + v.w;
    float q = v.x * v.x + v.y * v.y + v.z * v.z + v.w * v.w;
#pragma unroll
    for (int m = 32; m; m >>= 1) { s += __shfl_xor(s, m); q += __shfl_xor(q, m); }
    const float mu = s * (1.0f / Cc);
    const float rstd = rsqrtf(q * (1.0f / Cc) - mu * mu + LN_EPS);

    const float4 w4 = reinterpret_cast<const float4*>(nw)[lane];
    const float4 b4 = reinterpret_cast<const float4*>(nb)[lane];
    float4 y;
    y.x = (v.x - mu) * rstd * w4.x + b4.x;
    y.y = (v.y - mu) * rstd * w4.y + b4.y;
    y.z = (v.z - mu) * rstd * w4.z + b4.z;
    y.w = (v.w - mu) * rstd * w4.w + b4.w;
    reinterpret_cast<float4*>(n2)[row * 64 + lane] = y;

    float mx = fmaxf(fmaxf(y.x, y.y), fmaxf(y.z, y.w));
#pragma unroll
    for (int m = 32; m; m >>= 1) mx = fmaxf(mx, __shfl_xor(mx, m));
    float es = __expf(y.x - mx) + __expf(y.y - mx) + __expf(y.z - mx) + __expf(y.w - mx);
#pragma unroll
    for (int m = 32; m; m >>= 1) es += __shfl_xor(es, m);
    const float inv = 1.0f / es;
    const u16 q0 = f2bf(__expf(y.x - mx) * inv);
    const u16 q1 = f2bf(__expf(y.y - mx) * inv);
    const u16 q2 = f2bf(__expf(y.z - mx) * inv);
    const u16 q3 = f2bf(__expf(y.w - mx) * inv);
    int2 pk;
    pk.x = (int)((unsigned)q0 | ((unsigned)q1 << 16));
    pk.y = (int)((unsigned)q2 | ((unsigned)q3 << 16));
    *reinterpret_cast<int2*>(Qexp + row * Cc + lane * 4) = pk;
}

// ---------------- K2a: per-(b,d) online softmax stats over n, partial per 256-row chunk
__global__ __launch_bounds__(256) void k_colstat_part(const float* __restrict__ n2,
                                                      float* __restrict__ pM,
                                                      float* __restrict__ pS) {
    const int d = threadIdx.x, ch = blockIdx.x, b = blockIdx.y;
    const float* base = n2 + ((long long)b * Nn + (long long)ch * 256) * Cc + d;
    float m = -INFINITY, s = 0.0f;
    for (int r = 0; r < 256; ++r) {
        const float x = base[(long long)r * Cc];
        const float nm = fmaxf(m, x);
        s = s * __expf(m - nm) + __expf(x - nm);
        m = nm;
    }
    pM[(b * 36 + ch) * Cc + d] = m;
    pS[(b * 36 + ch) * Cc + d] = s;
}

// ---------------- K2b: combine 36 chunk partials
__global__ __launch_bounds__(256) void k_colstat_comb(const float* __restrict__ pM,
                                                      const float* __restrict__ pS,
                                                      float* __restrict__ colM,
                                                      float* __restrict__ colS) {
    const int d = threadIdx.x, b = blockIdx.x;
    float m = -INFINITY, s = 0.0f;
    for (int ch = 0; ch < 36; ++ch) {
        const float cm = pM[(b * 36 + ch) * Cc + d];
        const float cs = pS[(b * 36 + ch) * Cc + d];
        const float nm = fmaxf(m, cm);
        s = s * __expf(m - nm) + cs * __expf(cm - nm);
        m = nm;
    }
    colM[b * Cc + d] = m;
    colS[b * Cc + d] = s;
}

// ---------------- K3: context partials: ctxp[kc][b][d][e] = sum_{n in chunk} keyv[d,n]*values[n,e]
// values computed inline = LN(x1). grid (16, KSPLIT, 8), block 256.
__global__ __launch_bounds__(256) void k_ctx(const float* __restrict__ n2,
                                             const float* __restrict__ x1,
                                             const float* __restrict__ x1mu,
                                             const float* __restrict__ x1rs,
                                             const float* __restrict__ lnw,
                                             const float* __restrict__ lnb,
                                             const float* __restrict__ colM,
                                             const float* __restrict__ colS,
                                             float* __restrict__ ctxp) {
    __shared__ float As[16][64], Bs[16][64];
    __shared__ float Md[64], iS[64], wv[64], bv[64];
    const int b = blockIdx.z, kc = blockIdx.y;
    const int d0 = (blockIdx.x >> 2) * 64, e0 = (blockIdx.x & 3) * 64;
    const int t = threadIdx.x, tx = t & 15, ty = t >> 4;
    if (t < 64) {
        Md[t] = colM[b * Cc + d0 + t];
        iS[t] = 1.0f / colS[b * Cc + d0 + t];
        wv[t] = lnw[e0 + t];
        bv[t] = lnb[e0 + t];
    }
    const int s_kk = t >> 4, s_d4 = (t & 15) * 4;
    float acc[4][4] = {{0.f}};
    __syncthreads();
    for (int it = 0; it < 64; ++it) {
        const long long nrow = (long long)b * Nn + kc * 1024 + it * 16 + s_kk;
        const float4 xa = *reinterpret_cast<const float4*>(n2 + nrow * Cc + d0 + s_d4);
        const float4 x4 = *reinterpret_cast<const float4*>(x1 + nrow * Cc + e0 + s_d4);
        const float mu = x1mu[nrow], rs = x1rs[nrow];
        float4 ea, xb;
        ea.x = __expf(xa.x - Md[s_d4 + 0]) * iS[s_d4 + 0];
        ea.y = __expf(xa.y - Md[s_d4 + 1]) * iS[s_d4 + 1];
        ea.z = __expf(xa.z - Md[s_d4 + 2]) * iS[s_d4 + 2];
        ea.w = __expf(xa.w - Md[s_d4 + 3]) * iS[s_d4 + 3];
        xb.x = (x4.x - mu) * rs * wv[s_d4 + 0] + bv[s_d4 + 0];
        xb.y = (x4.y - mu) * rs * wv[s_d4 + 1] + bv[s_d4 + 1];
        xb.z = (x4.z - mu) * rs * wv[s_d4 + 2] + bv[s_d4 + 2];
        xb.w = (x4.w - mu) * rs * wv[s_d4 + 3] + bv[s_d4 + 3];
        __syncthreads();
        *reinterpret_cast<float4*>(&As[s_kk][s_d4]) = ea;
        *reinterpret_cast<float4*>(&Bs[s_kk][s_d4]) = xb;
        __syncthreads();
#pragma unroll
        for (int kk = 0; kk < 16; ++kk) {
            const float4 a4 = *reinterpret_cast<const float4*>(&As[kk][ty * 4]);
            const float4 b4 = *reinterpret_cast<const float4*>(&Bs[kk][tx * 4]);
            const float aa[4] = {a4.x, a4.y, a4.z, a4.w};
            const float bb[4] = {b4.x, b4.y, b4.z, b4.w};
#pragma unroll
            for (int i = 0; i < 4; ++i)
#pragma unroll
                for (int j = 0; j < 4; ++j) acc[i][j] = fmaf(aa[i], bb[j], acc[i][j]);
        }
    }
#pragma unroll
    for (int i = 0; i < 4; ++i) {
        const float4 v = make_float4(acc[i][0], acc[i][1], acc[i][2], acc[i][3]);
        *reinterpret_cast<float4*>(ctxp + (((long long)kc * Bb + b) * Cc + d0 + ty * 4 + i) * Cc + e0 + tx * 4) = v;
    }
}

// ---------------- K3b: deterministic split-K reduction
__global__ __launch_bounds__(256) void k_ctxred(const float* __restrict__ ctxp,
                                                float* __restrict__ ctx) {
    const long long i4 = ((long long)blockIdx.x * 256 + threadIdx.x) * 4;
    float4 s = make_float4(0.f, 0.f, 0.f, 0.f);
    for (int kc = 0; kc < KSPLIT; ++kc) {
        const float4 v = *reinterpret_cast<const float4*>(ctxp + (long long)kc * (Bb * Cc * Cc) + i4);
        s.x += v.x; s.y += v.y; s.z += v.z; s.w += v.w;
    }
    *reinterpret_cast<float4*>(ctx + i4) = s;
}

// ---------------- K4: rank + combined top-k softmax coefficients. block per (b,d) row.
__global__ __launch_bounds__(256) void k_rank(const float* __restrict__ ctx,
                                              const float* __restrict__ aw,
                                              float* __restrict__ Ac) {
    __shared__ float row[256];
    __shared__ float red[256];
    const int d = blockIdx.x, b = blockIdx.y, e = threadIdx.x;
    const float c = ctx[((long long)(b * Cc + d)) * Cc + e];
    row[e] = c;
    __syncthreads();
    int p = 0;
    for (int j = 0; j < 256; ++j) {
        const float cj = row[j];
        p += (cj > c) || (cj == c && j < e);  // stable top_k rank (0-based)
    }
    red[e] = c; __syncthreads();
    for (int s_ = 128; s_; s_ >>= 1) { if (e < s_) red[e] = fmaxf(red[e], red[e + s_]); __syncthreads(); }
    const float m = red[0];
    const float ex = __expf(c - m);
    const int kks[4] = {128, 170, 192, 204};
    float Zv[4];
#pragma unroll
    for (int i = 0; i < 4; ++i) {
        __syncthreads();
        red[e] = (p < kks[i]) ? ex : 0.0f;
        __syncthreads();
        for (int s_ = 128; s_; s_ >>= 1) { if (e < s_) red[e] += red[e + s_]; __syncthreads(); }
        Zv[i] = red[0];
    }
    float wsum = 0.0f;
#pragma unroll
    for (int i = 0; i < 4; ++i)
        if (p < kks[i]) wsum += aw[i] / Zv[i];
    Ac[((long long)(b * Cc + d)) * Cc + e] = ex * wsum;
}

// ---------------- K5: WA[b,o,e] = sum_d W[o,d] * A[b,d,e] -> bf16. grid (32, 8), block 256.
__global__ __launch_bounds__(256) void k_wa(const float* __restrict__ W,
                                            const float* __restrict__ Ac,
                                            u16* __restrict__ WAb16) {
    __shared__ float As[16][64], Bs[16][64];
    const int b = blockIdx.y;
    const int o0 = (blockIdx.x >> 2) * 64, e0 = (blockIdx.x & 3) * 64;
    const int t = threadIdx.x, tx = t & 15, ty = t >> 4;
    const int a_oo = t >> 2, a_k4 = (t & 3) * 4;
    const int b_kk = t >> 4, b_e4 = (t & 15) * 4;
    float acc[4][4] = {{0.f}};
    for (int kd = 0; kd < 256; kd += 16) {
        const float4 wv = *reinterpret_cast<const float4*>(W + (o0 + a_oo) * Cc + kd + a_k4);
        const float4 av = *reinterpret_cast<const float4*>(Ac + ((long long)(b * Cc + kd + b_kk)) * Cc + e0 + b_e4);
        __syncthreads();
        As[a_k4 + 0][a_oo] = wv.x; As[a_k4 + 1][a_oo] = wv.y;
        As[a_k4 + 2][a_oo] = wv.z; As[a_k4 + 3][a_oo] = wv.w;
        *reinterpret_cast<float4*>(&Bs[b_kk][b_e4]) = av;
        __syncthreads();
#pragma unroll
        for (int kk = 0; kk < 16; ++kk) {
            const float4 a4 = *reinterpret_cast<const float4*>(&As[kk][ty * 4]);
            const float4 b4 = *reinterpret_cast<const float4*>(&Bs[kk][tx * 4]);
            const float aa[4] = {a4.x, a4.y, a4.z, a4.w};
            const float bb[4] = {b4.x, b4.y, b4.z, b4.w};
#pragma unroll
            for (int i = 0; i < 4; ++i)
#pragma unroll
                for (int j = 0; j < 4; ++j) acc[i][j] = fmaf(aa[i], bb[j], acc[i][j]);
        }
    }
#pragma unroll
    for (int i = 0; i < 4; ++i) {
        int2 pk;
        pk.x = (int)((unsigned)f2bf(acc[i][0]) | ((unsigned)f2bf(acc[i][1]) << 16));
        pk.y = (int)((unsigned)f2bf(acc[i][2]) | ((unsigned)f2bf(acc[i][3]) << 16));
        *reinterpret_cast<int2*>(WAb16 + ((long long)(b * Oo + o0 + ty * 4 + i)) * Cc + e0 + tx * 4) = pk;
    }
}

// ---------------- K6: bf16 MFMA GEMM.  C[m][n] = sum_k A[m][k] * Bt[n][k]
// A: [M][K] bf16 row-major, Bt: [N][K] bf16 row-major, C: [M][N] f32.
// 128x128 tile, BK=64, 4 waves (2x2), XOR-swizzled LDS (write & read).
__global__ __launch_bounds__(256) void k_mm_bf16(const u16* __restrict__ A,
                                                 const u16* __restrict__ Bt,
                                                 float* __restrict__ C,
                                                 int lda, int ldb, int ldc,
                                                 long long sAb, long long sBb, long long sCb,
                                                 int kChunk, long long sCk,
                                                 int tilesN, int kIters) {
    __shared__ alignas(16) u16 Asm[128 * 64];
    __shared__ alignas(16) u16 Bsm[128 * 64];
    const int t = threadIdx.x;
    const int b = blockIdx.z, kc = blockIdx.y;
    const int tm = blockIdx.x / tilesN, tn = blockIdx.x % tilesN;
    const int m0 = tm * 128, n0 = tn * 128;
    const u16* Ag = A + b * sAb + (long long)kc * kChunk;
    const u16* Bg = Bt + b * sBb + (long long)kc * kChunk;
    float* Cg = C + b * sCb + (long long)kc * sCk;

    const int l = t & 63, w = t >> 6;
    const int wr = w >> 1, wc = w & 1;
    const int frow = l & 15, fk = (l >> 4) << 3;  // 0,8,16,24

    f32x4 acc[4][4] = {};

    for (int kt = 0; kt < kIters; ++kt) {
        const int k0 = kt * 64;
        int4 av[4], bv[4];
#pragma unroll
        for (int i = 0; i < 4; ++i) {
            const int s = t + 256 * i;
            const int r = s >> 3, c16 = s & 7;
            av[i] = *reinterpret_cast<const int4*>(Ag + (long long)(m0 + r) * lda + k0 + c16 * 8);
            bv[i] = *reinterpret_cast<const int4*>(Bg + (long long)(n0 + r) * ldb + k0 + c16 * 8);
        }
        __syncthreads();
#pragma unroll
        for (int i = 0; i < 4; ++i) {
            const int s = t + 256 * i;
            const int r = s >> 3, c16 = s & 7;
            const int idx = r * 64 + ((c16 * 8) ^ ((r & 7) << 3));
            *reinterpret_cast<int4*>(&Asm[idx]) = av[i];
            *reinterpret_cast<int4*>(&Bsm[idx]) = bv[i];
        }
        __syncthreads();
#pragma unroll
        for (int kf = 0; kf < 2; ++kf) {
            short8 af[4], bf[4];
            const int kk = kf * 32 + fk;
#pragma unroll
            for (int mi = 0; mi < 4; ++mi) {
                const int row = wr * 64 + mi * 16 + frow;
                af[mi] = *reinterpret_cast<const short8*>(&Asm[row * 64 + (kk ^ ((row & 7) << 3))]);
            }
#pragma unroll
            for (int ni = 0; ni < 4; ++ni) {
                const int row = wc * 64 + ni * 16 + frow;
                bf[ni] = *reinterpret_cast<const short8*>(&Bsm[row * 64 + (kk ^ ((row & 7) << 3))]);
            }
#pragma unroll
            for (int mi = 0; mi < 4; ++mi)
#pragma unroll
                for (int ni = 0; ni < 4; ++ni)
                    acc[mi][ni] = __builtin_amdgcn_mfma_f32_16x16x32_bf16(af[mi], bf[ni], acc[mi][ni], 0, 0, 0);
        }
    }

    const int crow0 = (l >> 4) * 4, ccol = l & 15;
#pragma unroll
    for (int mi = 0; mi < 4; ++mi) {
#pragma unroll
        for (int ni = 0; ni < 4; ++ni) {
            const int row = m0 + wr * 64 + mi * 16 + crow0;
            const int col = n0 + wc * 64 + ni * 16 + ccol;
#pragma unroll
            for (int r_ = 0; r_ < 4; ++r_)
                Cg[(long long)(row + r_) * ldc + col] = acc[mi][ni][r_];
        }
    }
}

// ---------------- K7: +bias, LayerNorm over O=512, transposed write out[b,o,n]. grid (576, 8).
__global__ __launch_bounds__(256) void k_ln2t(const float* __restrict__ rp,
                                              const float* __restrict__ rbias,
                                              const float* __restrict__ nw,
                                              const float* __restrict__ nb,
                                              float* __restrict__ out) {
    __shared__ float tile[16][520];
    __shared__ float psum[16][16], psq[16][16];
    __shared__ float mu[16], rs[16];
    const int b = blockIdx.y, n0 = blockIdx.x * 16, t = threadIdx.x;
#pragma unroll
    for (int i = 0; i < 8; ++i) {
        const int idx = i * 256 + t;
        const int r = idx >> 7;
        const int o4 = (idx & 127) * 4;
        float4 v = *reinterpret_cast<const float4*>(rp + ((long long)b * Nn + n0 + r) * Oo + o4);
        const float4 bb4 = *reinterpret_cast<const float4*>(rbias + o4);
        v.x += bb4.x; v.y += bb4.y; v.z += bb4.z; v.w += bb4.w;
        *reinterpret_cast<float4*>(&tile[r][o4]) = v;
    }
    __syncthreads();
    {
        const int r = t >> 4, sub = t & 15;
        float s = 0.f, q = 0.f;
#pragma unroll
        for (int i = 0; i < 32; ++i) { const float v = tile[r][sub + 16 * i]; s += v; q += v * v; }
        psum[r][sub] = s; psq[r][sub] = q;
    }
    __syncthreads();
    if (t < 16) {
        float s = 0.f, q = 0.f;
        for (int i = 0; i < 16; ++i) { s += psum[t][i]; q += psq[t][i]; }
        const float m = s * (1.0f / Oo);
        mu[t] = m;
        rs[t] = rsqrtf(q * (1.0f / Oo) - m * m + LN_EPS);
    }
    __syncthreads();
#pragma unroll
    for (int i = 0; i < 8; ++i) {
        const int o = (t >> 2) + 64 * i;
        const int rb_ = (t & 3) * 4;
        const float w = nw[o], bbv = nb[o];
        float4 v;
        v.x = (tile[rb_ + 0][o] - mu[rb_ + 0]) * rs[rb_ + 0] * w + bbv;
        v.y = (tile[rb_ + 1][o] - mu[rb_ + 1]) * rs[rb_ + 1] * w + bbv;
        v.z = (tile[rb_ + 2][o] - mu[rb_ + 2]) * rs[rb_ + 2] * w + bbv;
        v.w = (tile[rb_ + 3][o] - mu[rb_ + 3]) * rs[rb_ + 3] * w + bbv;
        *reinterpret_cast<float4*>(out + ((long long)(b * Oo + o)) * Nn + n0 + rb_) = v;
    }
}

extern "C" void kernel_launch(void* const* d_in, const int* in_sizes, int n_in,
                              void* d_out, int out_size, void* d_ws, size_t ws_size,
                              hipStream_t stream) {
    (void)in_sizes; (void)n_in; (void)out_size; (void)ws_size;
    const float* x1    = (const float*)d_in[0];
    const float* x2    = (const float*)d_in[1];
    const float* n1w   = (const float*)d_in[2];
    const float* n1b   = (const float*)d_in[3];
    const float* rw    = (const float*)d_in[4];
    const float* rbias = (const float*)d_in[5];
    const float* n2w   = (const float*)d_in[6];
    const float* n2b   = (const float*)d_in[7];
    const float* aw    = (const float*)d_in[8];
    float* out = (float*)d_out;

    // d_out doubles as scratch: Qexp (bf16) in first half, n2 (f32) in second half.
    // Both dead before the final k_ln2t overwrite.
    u16*   Qexp = (u16*)d_out;                                // 18,874,368 u16 = 9.44M floats
    float* n2   = out + (size_t)Bb * Nn * Cc;                 // second 18.87M floats

    float* ws = (float*)d_ws;
    size_t off = 0;
    float* rp     = ws + off; off += (size_t)Bb * Nn * Oo;            // 37,748,736
    float* ctxp   = ws + off; off += (size_t)KSPLIT * Bb * Cc * Cc;   //  4,718,592
    float* ctx    = ws + off; off += (size_t)Bb * Cc * Cc;            //    524,288
    float* Ac     = ws + off; off += (size_t)Bb * Cc * Cc;            //    524,288
    u16*   WAb16  = (u16*)(ws + off); off += (size_t)Bb * Oo * Cc / 2;//    524,288 u16
    float* pM     = ws + off; off += (size_t)Bb * 36 * Cc;
    float* pS     = ws + off; off += (size_t)Bb * 36 * Cc;
    float* colM   = ws + off; off += (size_t)Bb * Cc;
    float* colS   = ws + off; off += (size_t)Bb * Cc;
    float* x1mu   = ws + off; off += (size_t)Bb * Nn;
    float* x1rs   = ws + off; off += (size_t)Bb * Nn;

    k_stat1<<<dim3(Bb * Nn / 4), 256, 0, stream>>>(x1, x1mu, x1rs);
    k_ln<<<dim3(Bb * Nn / 4), 256, 0, stream>>>(x2, n1w, n1b, n2, Qexp);
    k_colstat_part<<<dim3(36, Bb), 256, 0, stream>>>(n2, pM, pS);
    k_colstat_comb<<<dim3(Bb), 256, 0, stream>>>(pM, pS, colM, colS);
    k_ctx<<<dim3(16, KSPLIT, Bb), 256, 0, stream>>>(n2, x1, x1mu, x1rs, n1w, n1b, colM, colS, ctxp);
    k_ctxred<<<dim3(512), 256, 0, stream>>>(ctxp, ctx);
    k_rank<<<dim3(Cc, Bb), 256, 0, stream>>>(ctx, aw, Ac);
    k_wa<<<dim3(32, Bb), 256, 0, stream>>>(rw, Ac, WAb16);
    // rp[b][n][o] = sum_e Qexp[b][n][e] * WA[b][o][e]
    k_mm_bf16<<<dim3((Nn / 128) * (Oo / 128), 1, Bb), 256, 0, stream>>>(
        Qexp, WAb16, rp,
        Cc, Cc, Oo,
        (long long)Nn * Cc, (long long)Oo * Cc, (long long)Nn * Oo,
        0, 0,
        Oo / 128, Cc / 64);
    k_ln2t<<<dim3(576, Bb), 256, 0, stream>>>(rp, rbias, n2w, n2b, out);
}

// Round 3
// 430.203 us; speedup vs baseline: 1.4400x; 1.1423x over previous
//
#include <hip/hip_runtime.h>
#include <math.h>

typedef __attribute__((ext_vector_type(8))) short short8;
typedef __attribute__((ext_vector_type(4))) float f32x4;
typedef unsigned short u16;

constexpr int Bb = 8;
constexpr int Nn = 9216;   // 96*96
constexpr int Cc = 256;    // = D
constexpr int Oo = 512;    // 2C
constexpr float LN_EPS = 1e-5f;
constexpr int KS2 = 8;     // ctx GEMM split-K chunks (9216 = 8*1152)

static __device__ __forceinline__ u16 f2bf(float f) {
    unsigned u = __builtin_bit_cast(unsigned, f);
    u += 0x7fffu + ((u >> 16) & 1u);   // RNE
    return (u16)(u >> 16);
}
static __device__ __forceinline__ float bf2f(u16 u) {
    return __builtin_bit_cast(float, (unsigned)u << 16);
}

// ---------------- K0: per-row mean/rstd of x1 and x2 (grid.y selects source)
__global__ __launch_bounds__(256) void k_stat(const float* __restrict__ x1,
                                              const float* __restrict__ x2,
                                              float* __restrict__ x1mu,
                                              float* __restrict__ x1rs,
                                              float* __restrict__ x2mu,
                                              float* __restrict__ x2rs) {
    const int lane = threadIdx.x & 63;
    const long long row = (long long)blockIdx.x * 4 + (threadIdx.x >> 6);
    const int which = blockIdx.y;
    const float* x = which ? x2 : x1;
    const float4 v = reinterpret_cast<const float4*>(x)[row * 64 + lane];
    float s = v.x + v.y + v.z + v.w;
    float q = v.x * v.x + v.y * v.y + v.z * v.z + v.w * v.w;
#pragma unroll
    for (int m = 32; m; m >>= 1) { s += __shfl_xor(s, m); q += __shfl_xor(q, m); }
    const float mu = s * (1.0f / Cc);
    const float rstd = rsqrtf(q * (1.0f / Cc) - mu * mu + LN_EPS);
    if (lane == 0) {
        if (which) { x2mu[row] = mu; x2rs[row] = rstd; }
        else       { x1mu[row] = mu; x1rs[row] = rstd; }
    }
}

// ---------------- K1: LN(x2) -> row-softmax exp -> Qexp (bf16, row-major [n][e])
__global__ __launch_bounds__(256) void k_ln(const float* __restrict__ x2,
                                            const float* __restrict__ nw,
                                            const float* __restrict__ nb,
                                            u16* __restrict__ Qexp) {
    const int lane = threadIdx.x & 63;
    const long long row = (long long)blockIdx.x * 4 + (threadIdx.x >> 6);

    const float4 v = reinterpret_cast<const float4*>(x2)[row * 64 + lane];
    float s = v.x + v.y + v.z + v.w;
    float q = v.x * v.x + v.y * v.y + v.z * v.z + v.w * v.w;
#pragma unroll
    for (int m = 32; m; m >>= 1) { s += __shfl_xor(s, m); q += __shfl_xor(q, m); }
    const float mu = s * (1.0f / Cc);
    const float rstd = rsqrtf(q * (1.0f / Cc) - mu * mu + LN_EPS);

    const float4 w4 = reinterpret_cast<const float4*>(nw)[lane];
    const float4 b4 = reinterpret_cast<const float4*>(nb)[lane];
    float4 y;
    y.x = (v.x - mu) * rstd * w4.x + b4.x;
    y.y = (v.y - mu) * rstd * w4.y + b4.y;
    y.z = (v.z - mu) * rstd * w4.z + b4.z;
    y.w = (v.w - mu) * rstd * w4.w + b4.w;

    float mx = fmaxf(fmaxf(y.x, y.y), fmaxf(y.z, y.w));
#pragma unroll
    for (int m = 32; m; m >>= 1) mx = fmaxf(mx, __shfl_xor(mx, m));
    float es = __expf(y.x - mx) + __expf(y.y - mx) + __expf(y.z - mx) + __expf(y.w - mx);
#pragma unroll
    for (int m = 32; m; m >>= 1) es += __shfl_xor(es, m);
    const float inv = 1.0f / es;
    const u16 q0 = f2bf(__expf(y.x - mx) * inv);
    const u16 q1 = f2bf(__expf(y.y - mx) * inv);
    const u16 q2 = f2bf(__expf(y.z - mx) * inv);
    const u16 q3 = f2bf(__expf(y.w - mx) * inv);
    int2 pk;
    pk.x = (int)((unsigned)q0 | ((unsigned)q1 << 16));
    pk.y = (int)((unsigned)q2 | ((unsigned)q3 << 16));
    *reinterpret_cast<int2*>(Qexp + row * Cc + lane * 4) = pk;
}

// ---------------- K2: tiled LN(+exp) transpose: src [b][n][d] f32 -> dstT [b][d][n] bf16.
// doExp: also emit per-d partial sums of exp over the 64-n chunk -> pS[b][chunk][d].
// grid (144, 4, 8): x = n-chunk(64), y = d-tile(64), z = b. block 256.
__global__ __launch_bounds__(256) void k_T(const float* __restrict__ src,
                                           const float* __restrict__ mu,
                                           const float* __restrict__ rs,
                                           const float* __restrict__ lnw,
                                           const float* __restrict__ lnb,
                                           u16* __restrict__ dstT,
                                           float* __restrict__ pS,
                                           int doExp) {
    __shared__ u16 tile[64][72];   // [d][n], pad 72 u16 = 144 B rows (16B aligned)
    const int b = blockIdx.z, dt = blockIdx.y, nc = blockIdx.x;
    const int d0 = dt * 64, n0 = nc * 64;
    const int t = threadIdx.x;
    const int ln_ = t >> 4;        // 0..15  n-row within pass
    const int dc = t & 15;         // d float4 group
    const float4 w4 = *reinterpret_cast<const float4*>(lnw + d0 + dc * 4);
    const float4 b4 = *reinterpret_cast<const float4*>(lnb + d0 + dc * 4);
#pragma unroll
    for (int p = 0; p < 4; ++p) {
        const int nl = p * 16 + ln_;
        const long long row = (long long)b * Nn + n0 + nl;
        const float4 v = *reinterpret_cast<const float4*>(src + row * Cc + d0 + dc * 4);
        const float m_ = mu[row], r_ = rs[row];
        float y0 = (v.x - m_) * r_ * w4.x + b4.x;
        float y1 = (v.y - m_) * r_ * w4.y + b4.y;
        float y2 = (v.z - m_) * r_ * w4.z + b4.z;
        float y3 = (v.w - m_) * r_ * w4.w + b4.w;
        if (doExp) { y0 = __expf(y0); y1 = __expf(y1); y2 = __expf(y2); y3 = __expf(y3); }
        tile[dc * 4 + 0][nl] = f2bf(y0);
        tile[dc * 4 + 1][nl] = f2bf(y1);
        tile[dc * 4 + 2][nl] = f2bf(y2);
        tile[dc * 4 + 3][nl] = f2bf(y3);
    }
    __syncthreads();
#pragma unroll
    for (int p = 0; p < 2; ++p) {
        const int r = p * 32 + (t >> 3);
        const int c = (t & 7) * 8;
        const int4 v = *reinterpret_cast<const int4*>(&tile[r][c]);
        *reinterpret_cast<int4*>(dstT + ((long long)(b * Cc + d0 + r)) * Nn + n0 + c) = v;
    }
    if (doExp) {
        const int d = t >> 2, part = t & 3;
        const int4 u0 = *reinterpret_cast<const int4*>(&tile[d][part * 16]);
        const int4 u1 = *reinterpret_cast<const int4*>(&tile[d][part * 16 + 8]);
        float s = 0.f;
        const int us[8] = {u0.x, u0.y, u0.z, u0.w, u1.x, u1.y, u1.z, u1.w};
#pragma unroll
        for (int i = 0; i < 8; ++i) {
            s += bf2f((u16)(us[i] & 0xffff));
            s += bf2f((u16)(((unsigned)us[i]) >> 16));
        }
        s += __shfl_xor(s, 1);
        s += __shfl_xor(s, 2);
        if (part == 0) pS[((long long)b * 144 + nc) * Cc + d0 + d] = s;
    }
}

// ---------------- K2b: colS[b][d] = sum over 144 chunks
__global__ __launch_bounds__(256) void k_colcomb(const float* __restrict__ pS,
                                                 float* __restrict__ colS) {
    const int d = threadIdx.x, b = blockIdx.x;
    float s = 0.f;
    for (int c = 0; c < 144; ++c) s += pS[((long long)b * 144 + c) * Cc + d];
    colS[b * Cc + d] = s;
}

// ---------------- K6: bf16 MFMA GEMM.  C[m][n] = sum_k A[m][k] * Bt[n][k]
__global__ __launch_bounds__(256) void k_mm_bf16(const u16* __restrict__ A,
                                                 const u16* __restrict__ Bt,
                                                 float* __restrict__ C,
                                                 int lda, int ldb, int ldc,
                                                 long long sAb, long long sBb, long long sCb,
                                                 int kChunk, long long sCk,
                                                 int tilesN, int kIters) {
    __shared__ alignas(16) u16 Asm[128 * 64];
    __shared__ alignas(16) u16 Bsm[128 * 64];
    const int t = threadIdx.x;
    const int b = blockIdx.z, kc = blockIdx.y;
    const int tm = blockIdx.x / tilesN, tn = blockIdx.x % tilesN;
    const int m0 = tm * 128, n0 = tn * 128;
    const u16* Ag = A + b * sAb + (long long)kc * kChunk;
    const u16* Bg = Bt + b * sBb + (long long)kc * kChunk;
    float* Cg = C + b * sCb + (long long)kc * sCk;

    const int l = t & 63, w = t >> 6;
    const int wr = w >> 1, wc = w & 1;
    const int frow = l & 15, fk = (l >> 4) << 3;

    f32x4 acc[4][4] = {};

    for (int kt = 0; kt < kIters; ++kt) {
        const int k0 = kt * 64;
        int4 av[4], bv[4];
#pragma unroll
        for (int i = 0; i < 4; ++i) {
            const int s = t + 256 * i;
            const int r = s >> 3, c16 = s & 7;
            av[i] = *reinterpret_cast<const int4*>(Ag + (long long)(m0 + r) * lda + k0 + c16 * 8);
            bv[i] = *reinterpret_cast<const int4*>(Bg + (long long)(n0 + r) * ldb + k0 + c16 * 8);
        }
        __syncthreads();
#pragma unroll
        for (int i = 0; i < 4; ++i) {
            const int s = t + 256 * i;
            const int r = s >> 3, c16 = s & 7;
            const int idx = r * 64 + ((c16 * 8) ^ ((r & 7) << 3));
            *reinterpret_cast<int4*>(&Asm[idx]) = av[i];
            *reinterpret_cast<int4*>(&Bsm[idx]) = bv[i];
        }
        __syncthreads();
#pragma unroll
        for (int kf = 0; kf < 2; ++kf) {
            short8 af[4], bf[4];
            const int kk = kf * 32 + fk;
#pragma unroll
            for (int mi = 0; mi < 4; ++mi) {
                const int row = wr * 64 + mi * 16 + frow;
                af[mi] = *reinterpret_cast<const short8*>(&Asm[row * 64 + (kk ^ ((row & 7) << 3))]);
            }
#pragma unroll
            for (int ni = 0; ni < 4; ++ni) {
                const int row = wc * 64 + ni * 16 + frow;
                bf[ni] = *reinterpret_cast<const short8*>(&Bsm[row * 64 + (kk ^ ((row & 7) << 3))]);
            }
#pragma unroll
            for (int mi = 0; mi < 4; ++mi)
#pragma unroll
                for (int ni = 0; ni < 4; ++ni)
                    acc[mi][ni] = __builtin_amdgcn_mfma_f32_16x16x32_bf16(af[mi], bf[ni], acc[mi][ni], 0, 0, 0);
        }
    }

    const int crow0 = (l >> 4) * 4, ccol = l & 15;
#pragma unroll
    for (int mi = 0; mi < 4; ++mi) {
#pragma unroll
        for (int ni = 0; ni < 4; ++ni) {
            const int row = m0 + wr * 64 + mi * 16 + crow0;
            const int col = n0 + wc * 64 + ni * 16 + ccol;
#pragma unroll
            for (int r_ = 0; r_ < 4; ++r_)
                Cg[(long long)(row + r_) * ldc + col] = acc[mi][ni][r_];
        }
    }
}

// ---------------- K3b: split-K reduction + 1/colS row scale
__global__ __launch_bounds__(256) void k_ctxred(const float* __restrict__ ctxp,
                                                const float* __restrict__ colS,
                                                float* __restrict__ ctx) {
    const long long i4 = ((long long)blockIdx.x * 256 + threadIdx.x) * 4;
    float4 s = make_float4(0.f, 0.f, 0.f, 0.f);
    for (int kc = 0; kc < KS2; ++kc) {
        const float4 v = *reinterpret_cast<const float4*>(ctxp + (long long)kc * (Bb * Cc * Cc) + i4);
        s.x += v.x; s.y += v.y; s.z += v.z; s.w += v.w;
    }
    const int b = (int)(i4 >> 16);
    const int d = ((int)(i4 >> 8)) & 255;
    const float inv = 1.0f / colS[b * Cc + d];
    s.x *= inv; s.y *= inv; s.z *= inv; s.w *= inv;
    *reinterpret_cast<float4*>(ctx + i4) = s;
}

// ---------------- K4: rank + combined top-k softmax coefficients. block per (b,d) row.
__global__ __launch_bounds__(256) void k_rank(const float* __restrict__ ctx,
                                              const float* __restrict__ aw,
                                              float* __restrict__ Ac) {
    __shared__ float row[256];
    __shared__ float red[256];
    const int d = blockIdx.x, b = blockIdx.y, e = threadIdx.x;
    const float c = ctx[((long long)(b * Cc + d)) * Cc + e];
    row[e] = c;
    __syncthreads();
    int p = 0;
    for (int j = 0; j < 256; ++j) {
        const float cj = row[j];
        p += (cj > c) || (cj == c && j < e);  // stable top_k rank (0-based)
    }
    red[e] = c; __syncthreads();
    for (int s_ = 128; s_; s_ >>= 1) { if (e < s_) red[e] = fmaxf(red[e], red[e + s_]); __syncthreads(); }
    const float m = red[0];
    const float ex = __expf(c - m);
    const int kks[4] = {128, 170, 192, 204};
    float Zv[4];
#pragma unroll
    for (int i = 0; i < 4; ++i) {
        __syncthreads();
        red[e] = (p < kks[i]) ? ex : 0.0f;
        __syncthreads();
        for (int s_ = 128; s_; s_ >>= 1) { if (e < s_) red[e] += red[e + s_]; __syncthreads(); }
        Zv[i] = red[0];
    }
    float wsum = 0.0f;
#pragma unroll
    for (int i = 0; i < 4; ++i)
        if (p < kks[i]) wsum += aw[i] / Zv[i];
    Ac[((long long)(b * Cc + d)) * Cc + e] = ex * wsum;
}

// ---------------- K5: WA[b,o,e] = sum_d W[o,d] * A[b,d,e] -> bf16. grid (32, 8), block 256.
__global__ __launch_bounds__(256) void k_wa(const float* __restrict__ W,
                                            const float* __restrict__ Ac,
                                            u16* __restrict__ WAb16) {
    __shared__ float As[16][64], Bs[16][64];
    const int b = blockIdx.y;
    const int o0 = (blockIdx.x >> 2) * 64, e0 = (blockIdx.x & 3) * 64;
    const int t = threadIdx.x, tx = t & 15, ty = t >> 4;
    const int a_oo = t >> 2, a_k4 = (t & 3) * 4;
    const int b_kk = t >> 4, b_e4 = (t & 15) * 4;
    float acc[4][4] = {{0.f}};
    for (int kd = 0; kd < 256; kd += 16) {
        const float4 wv = *reinterpret_cast<const float4*>(W + (o0 + a_oo) * Cc + kd + a_k4);
        const float4 av = *reinterpret_cast<const float4*>(Ac + ((long long)(b * Cc + kd + b_kk)) * Cc + e0 + b_e4);
        __syncthreads();
        As[a_k4 + 0][a_oo] = wv.x; As[a_k4 + 1][a_oo] = wv.y;
        As[a_k4 + 2][a_oo] = wv.z; As[a_k4 + 3][a_oo] = wv.w;
        *reinterpret_cast<float4*>(&Bs[b_kk][b_e4]) = av;
        __syncthreads();
#pragma unroll
        for (int kk = 0; kk < 16; ++kk) {
            const float4 a4 = *reinterpret_cast<const float4*>(&As[kk][ty * 4]);
            const float4 b4 = *reinterpret_cast<const float4*>(&Bs[kk][tx * 4]);
            const float aa[4] = {a4.x, a4.y, a4.z, a4.w};
            const float bb[4] = {b4.x, b4.y, b4.z, b4.w};
#pragma unroll
            for (int i = 0; i < 4; ++i)
#pragma unroll
                for (int j = 0; j < 4; ++j) acc[i][j] = fmaf(aa[i], bb[j], acc[i][j]);
        }
    }
#pragma unroll
    for (int i = 0; i < 4; ++i) {
        int2 pk;
        pk.x = (int)((unsigned)f2bf(acc[i][0]) | ((unsigned)f2bf(acc[i][1]) << 16));
        pk.y = (int)((unsigned)f2bf(acc[i][2]) | ((unsigned)f2bf(acc[i][3]) << 16));
        *reinterpret_cast<int2*>(WAb16 + ((long long)(b * Oo + o0 + ty * 4 + i)) * Cc + e0 + tx * 4) = pk;
    }
}

// ---------------- K7: +bias, LayerNorm over O=512, transposed write out[b,o,n]. grid (576, 8).
__global__ __launch_bounds__(256) void k_ln2t(const float* __restrict__ rp,
                                              const float* __restrict__ rbias,
                                              const float* __restrict__ nw,
                                              const float* __restrict__ nb,
                                              float* __restrict__ out) {
    __shared__ float tile[16][520];
    __shared__ float psum[16][16], psq[16][16];
    __shared__ float mu[16], rs[16];
    const int b = blockIdx.y, n0 = blockIdx.x * 16, t = threadIdx.x;
#pragma unroll
    for (int i = 0; i < 8; ++i) {
        const int idx = i * 256 + t;
        const int r = idx >> 7;
        const int o4 = (idx & 127) * 4;
        float4 v = *reinterpret_cast<const float4*>(rp + ((long long)b * Nn + n0 + r) * Oo + o4);
        const float4 bb4 = *reinterpret_cast<const float4*>(rbias + o4);
        v.x += bb4.x; v.y += bb4.y; v.z += bb4.z; v.w += bb4.w;
        *reinterpret_cast<float4*>(&tile[r][o4]) = v;
    }
    __syncthreads();
    {
        const int r = t >> 4, sub = t & 15;
        float s = 0.f, q = 0.f;
#pragma unroll
        for (int i = 0; i < 32; ++i) { const float v = tile[r][sub + 16 * i]; s += v; q += v * v; }
        psum[r][sub] = s; psq[r][sub] = q;
    }
    __syncthreads();
    if (t < 16) {
        float s = 0.f, q = 0.f;
        for (int i = 0; i < 16; ++i) { s += psum[t][i]; q += psq[t][i]; }
        const float m = s * (1.0f / Oo);
        mu[t] = m;
        rs[t] = rsqrtf(q * (1.0f / Oo) - m * m + LN_EPS);
    }
    __syncthreads();
#pragma unroll
    for (int i = 0; i < 8; ++i) {
        const int o = (t >> 2) + 64 * i;
        const int rb_ = (t & 3) * 4;
        const float w = nw[o], bbv = nb[o];
        float4 v;
        v.x = (tile[rb_ + 0][o] - mu[rb_ + 0]) * rs[rb_ + 0] * w + bbv;
        v.y = (tile[rb_ + 1][o] - mu[rb_ + 1]) * rs[rb_ + 1] * w + bbv;
        v.z = (tile[rb_ + 2][o] - mu[rb_ + 2]) * rs[rb_ + 2] * w + bbv;
        v.w = (tile[rb_ + 3][o] - mu[rb_ + 3]) * rs[rb_ + 3] * w + bbv;
        *reinterpret_cast<float4*>(out + ((long long)(b * Oo + o)) * Nn + n0 + rb_) = v;
    }
}

extern "C" void kernel_launch(void* const* d_in, const int* in_sizes, int n_in,
                              void* d_out, int out_size, void* d_ws, size_t ws_size,
                              hipStream_t stream) {
    (void)in_sizes; (void)n_in; (void)out_size; (void)ws_size;
    const float* x1    = (const float*)d_in[0];
    const float* x2    = (const float*)d_in[1];
    const float* n1w   = (const float*)d_in[2];
    const float* n1b   = (const float*)d_in[3];
    const float* rw    = (const float*)d_in[4];
    const float* rbias = (const float*)d_in[5];
    const float* n2w   = (const float*)d_in[6];
    const float* n2b   = (const float*)d_in[7];
    const float* aw    = (const float*)d_in[8];
    float* out = (float*)d_out;

    // d_out doubles as scratch (all dead before k_ln2t's final overwrite):
    // [Qexp bf16 37.7MB][KexpT bf16 37.7MB][VT bf16 37.7MB] of 151MB total.
    u16* Qexp  = (u16*)d_out;
    u16* KexpT = Qexp + (size_t)Bb * Nn * Cc;
    u16* VT    = KexpT + (size_t)Bb * Nn * Cc;

    float* ws = (float*)d_ws;
    size_t off = 0;
    float* rp     = ws + off; off += (size_t)Bb * Nn * Oo;            // 37,748,736
    float* ctxp   = ws + off; off += (size_t)KS2 * Bb * Cc * Cc;      //  4,194,304
    float* ctx    = ws + off; off += (size_t)Bb * Cc * Cc;            //    524,288
    float* Ac     = ws + off; off += (size_t)Bb * Cc * Cc;            //    524,288
    u16*   WAb16  = (u16*)(ws + off); off += (size_t)Bb * Oo * Cc / 2;//    524,288
    float* pS     = ws + off; off += (size_t)Bb * 144 * Cc;           //    294,912
    float* colS   = ws + off; off += (size_t)Bb * Cc;
    float* x1mu   = ws + off; off += (size_t)Bb * Nn;
    float* x1rs   = ws + off; off += (size_t)Bb * Nn;
    float* x2mu   = ws + off; off += (size_t)Bb * Nn;
    float* x2rs   = ws + off; off += (size_t)Bb * Nn;

    k_stat<<<dim3(Bb * Nn / 4, 2), 256, 0, stream>>>(x1, x2, x1mu, x1rs, x2mu, x2rs);
    k_ln<<<dim3(Bb * Nn / 4), 256, 0, stream>>>(x2, n1w, n1b, Qexp);
    // KexpT = exp(LN(x2))^T (bf16) + column-sum partials; VT = LN(x1)^T (bf16)
    k_T<<<dim3(144, 4, Bb), 256, 0, stream>>>(x2, x2mu, x2rs, n1w, n1b, KexpT, pS, 1);
    k_T<<<dim3(144, 4, Bb), 256, 0, stream>>>(x1, x1mu, x1rs, n1w, n1b, VT, pS, 0);
    k_colcomb<<<dim3(Bb), 256, 0, stream>>>(pS, colS);
    // ctxp[kc][b][d][e] = sum_{n in chunk} KexpT[d][n] * VT[e][n]
    k_mm_bf16<<<dim3(4, KS2, Bb), 256, 0, stream>>>(
        KexpT, VT, ctxp,
        Nn, Nn, Cc,
        (long long)Cc * Nn, (long long)Cc * Nn, (long long)Cc * Cc,
        Nn / KS2, (long long)Bb * Cc * Cc,
        Cc / 128, (Nn / KS2) / 64);
    k_ctxred<<<dim3(512), 256, 0, stream>>>(ctxp, colS, ctx);
    k_rank<<<dim3(Cc, Bb), 256, 0, stream>>>(ctx, aw, Ac);
    k_wa<<<dim3(32, Bb), 256, 0, stream>>>(rw, Ac, WAb16);
    // rp[b][n][o] = sum_e Qexp[b][n][e] * WA[b][o][e]
    k_mm_bf16<<<dim3((Nn / 128) * (Oo / 128), 1, Bb), 256, 0, stream>>>(
        Qexp, WAb16, rp,
        Cc, Cc, Oo,
        (long long)Nn * Cc, (long long)Oo * Cc, (long long)Nn * Oo,
        0, 0,
        Oo / 128, Cc / 64);
    k_ln2t<<<dim3(576, Bb), 256, 0, stream>>>(rp, rbias, n2w, n2b, out);
}

// Round 4
// 352.950 us; speedup vs baseline: 1.7552x; 1.2189x over previous
//
#include <hip/hip_runtime.h>
#include <math.h>

typedef __attribute__((ext_vector_type(8))) short short8;
typedef __attribute__((ext_vector_type(4))) float f32x4;
typedef unsigned short u16;

constexpr int Bb = 8;
constexpr int Nn = 9216;   // 96*96
constexpr int Cc = 256;    // = D
constexpr int Oo = 512;    // 2C
constexpr float LN_EPS = 1e-5f;
constexpr int KS2 = 8;     // ctx GEMM split-K chunks (9216 = 8*1152)

static __device__ __forceinline__ u16 f2bf(float f) {
    unsigned u = __builtin_bit_cast(unsigned, f);
    u += 0x7fffu + ((u >> 16) & 1u);   // RNE
    return (u16)(u >> 16);
}
static __device__ __forceinline__ float bf2f(u16 u) {
    return __builtin_bit_cast(float, (unsigned)u << 16);
}

// ---------------- K0: per-row mean/rstd of x1 and x2 (grid.y selects source)
__global__ __launch_bounds__(256) void k_stat(const float* __restrict__ x1,
                                              const float* __restrict__ x2,
                                              float* __restrict__ x1mu,
                                              float* __restrict__ x1rs,
                                              float* __restrict__ x2mu,
                                              float* __restrict__ x2rs) {
    const int lane = threadIdx.x & 63;
    const long long row = (long long)blockIdx.x * 4 + (threadIdx.x >> 6);
    const int which = blockIdx.y;
    const float* x = which ? x2 : x1;
    const float4 v = reinterpret_cast<const float4*>(x)[row * 64 + lane];
    float s = v.x + v.y + v.z + v.w;
    float q = v.x * v.x + v.y * v.y + v.z * v.z + v.w * v.w;
#pragma unroll
    for (int m = 32; m; m >>= 1) { s += __shfl_xor(s, m); q += __shfl_xor(q, m); }
    const float mu = s * (1.0f / Cc);
    const float rstd = rsqrtf(q * (1.0f / Cc) - mu * mu + LN_EPS);
    if (lane == 0) {
        if (which) { x2mu[row] = mu; x2rs[row] = rstd; }
        else       { x1mu[row] = mu; x1rs[row] = rstd; }
    }
}

// ---------------- K1: LN(x2) -> row-softmax exp -> Qexp (bf16, row-major [n][e])
__global__ __launch_bounds__(256) void k_ln(const float* __restrict__ x2,
                                            const float* __restrict__ nw,
                                            const float* __restrict__ nb,
                                            u16* __restrict__ Qexp) {
    const int lane = threadIdx.x & 63;
    const long long row = (long long)blockIdx.x * 4 + (threadIdx.x >> 6);

    const float4 v = reinterpret_cast<const float4*>(x2)[row * 64 + lane];
    float s = v.x + v.y + v.z + v.w;
    float q = v.x * v.x + v.y * v.y + v.z * v.z + v.w * v.w;
#pragma unroll
    for (int m = 32; m; m >>= 1) { s += __shfl_xor(s, m); q += __shfl_xor(q, m); }
    const float mu = s * (1.0f / Cc);
    const float rstd = rsqrtf(q * (1.0f / Cc) - mu * mu + LN_EPS);

    const float4 w4 = reinterpret_cast<const float4*>(nw)[lane];
    const float4 b4 = reinterpret_cast<const float4*>(nb)[lane];
    float4 y;
    y.x = (v.x - mu) * rstd * w4.x + b4.x;
    y.y = (v.y - mu) * rstd * w4.y + b4.y;
    y.z = (v.z - mu) * rstd * w4.z + b4.z;
    y.w = (v.w - mu) * rstd * w4.w + b4.w;

    float mx = fmaxf(fmaxf(y.x, y.y), fmaxf(y.z, y.w));
#pragma unroll
    for (int m = 32; m; m >>= 1) mx = fmaxf(mx, __shfl_xor(mx, m));
    float es = __expf(y.x - mx) + __expf(y.y - mx) + __expf(y.z - mx) + __expf(y.w - mx);
#pragma unroll
    for (int m = 32; m; m >>= 1) es += __shfl_xor(es, m);
    const float inv = 1.0f / es;
    const u16 q0 = f2bf(__expf(y.x - mx) * inv);
    const u16 q1 = f2bf(__expf(y.y - mx) * inv);
    const u16 q2 = f2bf(__expf(y.z - mx) * inv);
    const u16 q3 = f2bf(__expf(y.w - mx) * inv);
    int2 pk;
    pk.x = (int)((unsigned)q0 | ((unsigned)q1 << 16));
    pk.y = (int)((unsigned)q2 | ((unsigned)q3 << 16));
    *reinterpret_cast<int2*>(Qexp + row * Cc + lane * 4) = pk;
}

// ---------------- K2: tiled LN(+exp) transpose: src [b][n][d] f32 -> dstT [b][d][n] bf16.
// doExp: also emit per-d partial sums of exp over the 64-n chunk -> pS[b][chunk][d].
// grid (144, 4, 8): x = n-chunk(64), y = d-tile(64), z = b. block 256.
__global__ __launch_bounds__(256) void k_T(const float* __restrict__ src,
                                           const float* __restrict__ mu,
                                           const float* __restrict__ rs,
                                           const float* __restrict__ lnw,
                                           const float* __restrict__ lnb,
                                           u16* __restrict__ dstT,
                                           float* __restrict__ pS,
                                           int doExp) {
    __shared__ u16 tile[64][72];   // [d][n], pad 72 u16 = 144 B rows (16B aligned)
    const int b = blockIdx.z, dt = blockIdx.y, nc = blockIdx.x;
    const int d0 = dt * 64, n0 = nc * 64;
    const int t = threadIdx.x;
    const int ln_ = t >> 4;        // 0..15  n-row within pass
    const int dc = t & 15;         // d float4 group
    const float4 w4 = *reinterpret_cast<const float4*>(lnw + d0 + dc * 4);
    const float4 b4 = *reinterpret_cast<const float4*>(lnb + d0 + dc * 4);
#pragma unroll
    for (int p = 0; p < 4; ++p) {
        const int nl = p * 16 + ln_;
        const long long row = (long long)b * Nn + n0 + nl;
        const float4 v = *reinterpret_cast<const float4*>(src + row * Cc + d0 + dc * 4);
        const float m_ = mu[row], r_ = rs[row];
        float y0 = (v.x - m_) * r_ * w4.x + b4.x;
        float y1 = (v.y - m_) * r_ * w4.y + b4.y;
        float y2 = (v.z - m_) * r_ * w4.z + b4.z;
        float y3 = (v.w - m_) * r_ * w4.w + b4.w;
        if (doExp) { y0 = __expf(y0); y1 = __expf(y1); y2 = __expf(y2); y3 = __expf(y3); }
        tile[dc * 4 + 0][nl] = f2bf(y0);
        tile[dc * 4 + 1][nl] = f2bf(y1);
        tile[dc * 4 + 2][nl] = f2bf(y2);
        tile[dc * 4 + 3][nl] = f2bf(y3);
    }
    __syncthreads();
#pragma unroll
    for (int p = 0; p < 2; ++p) {
        const int r = p * 32 + (t >> 3);
        const int c = (t & 7) * 8;
        const int4 v = *reinterpret_cast<const int4*>(&tile[r][c]);
        *reinterpret_cast<int4*>(dstT + ((long long)(b * Cc + d0 + r)) * Nn + n0 + c) = v;
    }
    if (doExp) {
        const int d = t >> 2, part = t & 3;
        const int4 u0 = *reinterpret_cast<const int4*>(&tile[d][part * 16]);
        const int4 u1 = *reinterpret_cast<const int4*>(&tile[d][part * 16 + 8]);
        float s = 0.f;
        const int us[8] = {u0.x, u0.y, u0.z, u0.w, u1.x, u1.y, u1.z, u1.w};
#pragma unroll
        for (int i = 0; i < 8; ++i) {
            s += bf2f((u16)(us[i] & 0xffff));
            s += bf2f((u16)(((unsigned)us[i]) >> 16));
        }
        s += __shfl_xor(s, 1);
        s += __shfl_xor(s, 2);
        if (part == 0) pS[((long long)b * 144 + nc) * Cc + d0 + d] = s;
    }
}

// ---------------- K2b: colS[b][d] = sum over 144 chunks
__global__ __launch_bounds__(256) void k_colcomb(const float* __restrict__ pS,
                                                 float* __restrict__ colS) {
    const int d = threadIdx.x, b = blockIdx.x;
    float s = 0.f;
    for (int c = 0; c < 144; ++c) s += pS[((long long)b * 144 + c) * Cc + d];
    colS[b * Cc + d] = s;
}

// ---------------- K6: bf16 MFMA GEMM (ctx).  C[m][n] = sum_k A[m][k] * Bt[n][k]
__global__ __launch_bounds__(256) void k_mm_bf16(const u16* __restrict__ A,
                                                 const u16* __restrict__ Bt,
                                                 float* __restrict__ C,
                                                 int lda, int ldb, int ldc,
                                                 long long sAb, long long sBb, long long sCb,
                                                 int kChunk, long long sCk,
                                                 int tilesN, int kIters) {
    __shared__ alignas(16) u16 Asm[128 * 64];
    __shared__ alignas(16) u16 Bsm[128 * 64];
    const int t = threadIdx.x;
    const int b = blockIdx.z, kc = blockIdx.y;
    const int tm = blockIdx.x / tilesN, tn = blockIdx.x % tilesN;
    const int m0 = tm * 128, n0 = tn * 128;
    const u16* Ag = A + b * sAb + (long long)kc * kChunk;
    const u16* Bg = Bt + b * sBb + (long long)kc * kChunk;
    float* Cg = C + b * sCb + (long long)kc * sCk;

    const int l = t & 63, w = t >> 6;
    const int wr = w >> 1, wc = w & 1;
    const int frow = l & 15, fk = (l >> 4) << 3;

    f32x4 acc[4][4] = {};

    for (int kt = 0; kt < kIters; ++kt) {
        const int k0 = kt * 64;
        int4 av[4], bv[4];
#pragma unroll
        for (int i = 0; i < 4; ++i) {
            const int s = t + 256 * i;
            const int r = s >> 3, c16 = s & 7;
            av[i] = *reinterpret_cast<const int4*>(Ag + (long long)(m0 + r) * lda + k0 + c16 * 8);
            bv[i] = *reinterpret_cast<const int4*>(Bg + (long long)(n0 + r) * ldb + k0 + c16 * 8);
        }
        __syncthreads();
#pragma unroll
        for (int i = 0; i < 4; ++i) {
            const int s = t + 256 * i;
            const int r = s >> 3, c16 = s & 7;
            const int idx = r * 64 + ((c16 * 8) ^ ((r & 7) << 3));
            *reinterpret_cast<int4*>(&Asm[idx]) = av[i];
            *reinterpret_cast<int4*>(&Bsm[idx]) = bv[i];
        }
        __syncthreads();
#pragma unroll
        for (int kf = 0; kf < 2; ++kf) {
            short8 af[4], bf[4];
            const int kk = kf * 32 + fk;
#pragma unroll
            for (int mi = 0; mi < 4; ++mi) {
                const int row = wr * 64 + mi * 16 + frow;
                af[mi] = *reinterpret_cast<const short8*>(&Asm[row * 64 + (kk ^ ((row & 7) << 3))]);
            }
#pragma unroll
            for (int ni = 0; ni < 4; ++ni) {
                const int row = wc * 64 + ni * 16 + frow;
                bf[ni] = *reinterpret_cast<const short8*>(&Bsm[row * 64 + (kk ^ ((row & 7) << 3))]);
            }
#pragma unroll
            for (int mi = 0; mi < 4; ++mi)
#pragma unroll
                for (int ni = 0; ni < 4; ++ni)
                    acc[mi][ni] = __builtin_amdgcn_mfma_f32_16x16x32_bf16(af[mi], bf[ni], acc[mi][ni], 0, 0, 0);
        }
    }

    const int crow0 = (l >> 4) * 4, ccol = l & 15;
#pragma unroll
    for (int mi = 0; mi < 4; ++mi) {
#pragma unroll
        for (int ni = 0; ni < 4; ++ni) {
            const int row = m0 + wr * 64 + mi * 16 + crow0;
            const int col = n0 + wc * 64 + ni * 16 + ccol;
#pragma unroll
            for (int r_ = 0; r_ < 4; ++r_)
                Cg[(long long)(row + r_) * ldc + col] = acc[mi][ni][r_];
        }
    }
}

// ---------------- K3b: split-K reduction + 1/colS row scale
__global__ __launch_bounds__(256) void k_ctxred(const float* __restrict__ ctxp,
                                                const float* __restrict__ colS,
                                                float* __restrict__ ctx) {
    const long long i4 = ((long long)blockIdx.x * 256 + threadIdx.x) * 4;
    float4 s = make_float4(0.f, 0.f, 0.f, 0.f);
    for (int kc = 0; kc < KS2; ++kc) {
        const float4 v = *reinterpret_cast<const float4*>(ctxp + (long long)kc * (Bb * Cc * Cc) + i4);
        s.x += v.x; s.y += v.y; s.z += v.z; s.w += v.w;
    }
    const int b = (int)(i4 >> 16);
    const int d = ((int)(i4 >> 8)) & 255;
    const float inv = 1.0f / colS[b * Cc + d];
    s.x *= inv; s.y *= inv; s.z *= inv; s.w *= inv;
    *reinterpret_cast<float4*>(ctx + i4) = s;
}

// ---------------- K4: rank + combined top-k softmax coefficients. block per (b,d) row.
__global__ __launch_bounds__(256) void k_rank(const float* __restrict__ ctx,
                                              const float* __restrict__ aw,
                                              float* __restrict__ Ac) {
    __shared__ float row[256];
    __shared__ float red[256];
    const int d = blockIdx.x, b = blockIdx.y, e = threadIdx.x;
    const float c = ctx[((long long)(b * Cc + d)) * Cc + e];
    row[e] = c;
    __syncthreads();
    int p = 0;
    for (int j = 0; j < 256; ++j) {
        const float cj = row[j];
        p += (cj > c) || (cj == c && j < e);  // stable top_k rank (0-based)
    }
    red[e] = c; __syncthreads();
    for (int s_ = 128; s_; s_ >>= 1) { if (e < s_) red[e] = fmaxf(red[e], red[e + s_]); __syncthreads(); }
    const float m = red[0];
    const float ex = __expf(c - m);
    const int kks[4] = {128, 170, 192, 204};
    float Zv[4];
#pragma unroll
    for (int i = 0; i < 4; ++i) {
        __syncthreads();
        red[e] = (p < kks[i]) ? ex : 0.0f;
        __syncthreads();
        for (int s_ = 128; s_; s_ >>= 1) { if (e < s_) red[e] += red[e + s_]; __syncthreads(); }
        Zv[i] = red[0];
    }
    float wsum = 0.0f;
#pragma unroll
    for (int i = 0; i < 4; ++i)
        if (p < kks[i]) wsum += aw[i] / Zv[i];
    Ac[((long long)(b * Cc + d)) * Cc + e] = ex * wsum;
}

// ---------------- K5: WA[b,o,e] = sum_d W[o,d] * A[b,d,e] -> bf16. grid (32, 8), block 256.
__global__ __launch_bounds__(256) void k_wa(const float* __restrict__ W,
                                            const float* __restrict__ Ac,
                                            u16* __restrict__ WAb16) {
    __shared__ float As[16][64], Bs[16][64];
    const int b = blockIdx.y;
    const int o0 = (blockIdx.x >> 2) * 64, e0 = (blockIdx.x & 3) * 64;
    const int t = threadIdx.x, tx = t & 15, ty = t >> 4;
    const int a_oo = t >> 2, a_k4 = (t & 3) * 4;
    const int b_kk = t >> 4, b_e4 = (t & 15) * 4;
    float acc[4][4] = {{0.f}};
    for (int kd = 0; kd < 256; kd += 16) {
        const float4 wv = *reinterpret_cast<const float4*>(W + (o0 + a_oo) * Cc + kd + a_k4);
        const float4 av = *reinterpret_cast<const float4*>(Ac + ((long long)(b * Cc + kd + b_kk)) * Cc + e0 + b_e4);
        __syncthreads();
        As[a_k4 + 0][a_oo] = wv.x; As[a_k4 + 1][a_oo] = wv.y;
        As[a_k4 + 2][a_oo] = wv.z; As[a_k4 + 3][a_oo] = wv.w;
        *reinterpret_cast<float4*>(&Bs[b_kk][b_e4]) = av;
        __syncthreads();
#pragma unroll
        for (int kk = 0; kk < 16; ++kk) {
            const float4 a4 = *reinterpret_cast<const float4*>(&As[kk][ty * 4]);
            const float4 b4 = *reinterpret_cast<const float4*>(&Bs[kk][tx * 4]);
            const float aa[4] = {a4.x, a4.y, a4.z, a4.w};
            const float bb[4] = {b4.x, b4.y, b4.z, b4.w};
#pragma unroll
            for (int i = 0; i < 4; ++i)
#pragma unroll
                for (int j = 0; j < 4; ++j) acc[i][j] = fmaf(aa[i], bb[j], acc[i][j]);
        }
    }
#pragma unroll
    for (int i = 0; i < 4; ++i) {
        int2 pk;
        pk.x = (int)((unsigned)f2bf(acc[i][0]) | ((unsigned)f2bf(acc[i][1]) << 16));
        pk.y = (int)((unsigned)f2bf(acc[i][2]) | ((unsigned)f2bf(acc[i][3]) << 16));
        *reinterpret_cast<int2*>(WAb16 + ((long long)(b * Oo + o0 + ty * 4 + i)) * Cc + e0 + tx * 4) = pk;
    }
}

// ---------------- K7: fused reprojection GEMM + bias + LN(512) + transposed store.
// rp[n][o] = sum_e Qexp[n][e] * WA[o][e];  out[b][o][n] = LN_o(rp[n][:]+bias)*w+b
// grid (144, 1, 8), block 512 (8 waves, 2M x 4N). Tile: 64 n-rows x 512 o x K=256.
__global__ __launch_bounds__(512) void k_rpln(const u16* __restrict__ Qexp,
                                              const u16* __restrict__ WAb16,
                                              const float* __restrict__ rbias,
                                              const float* __restrict__ nw,
                                              const float* __restrict__ nb,
                                              float* __restrict__ out) {
    __shared__ alignas(16) u16 Asm[64 * 64];    // 8 KB
    __shared__ alignas(16) u16 Bsm[512 * 64];   // 64 KB (reused as f32 transpose patches)
    __shared__ float psum[64][4], psq[64][4];
    __shared__ float muA[64], rsA[64];

    const int t = threadIdx.x;
    const int b = blockIdx.z;
    const int n0 = blockIdx.x * 64;
    const int l = t & 63, w = t >> 6;
    const int wr = w >> 2, wc = w & 3;          // 2 (M) x 4 (N) waves
    const int frow = l & 15, fk = (l >> 4) << 3;

    f32x4 acc[2][8] = {};

    const u16* Ag = Qexp + ((long long)b * Nn + n0) * Cc;
    const u16* Bg = WAb16 + (long long)b * Oo * Cc;

    for (int kt = 0; kt < 4; ++kt) {
        const int k0 = kt * 64;
        int4 av;
        {
            const int r = t >> 3, c16 = t & 7;
            av = *reinterpret_cast<const int4*>(Ag + (long long)r * Cc + k0 + c16 * 8);
        }
        int4 bv[8];
#pragma unroll
        for (int p = 0; p < 8; ++p) {
            const int s = t + 512 * p;
            const int r = s >> 3, c16 = s & 7;
            bv[p] = *reinterpret_cast<const int4*>(Bg + (long long)r * Cc + k0 + c16 * 8);
        }
        __syncthreads();
        {
            const int r = t >> 3, c16 = t & 7;
            *reinterpret_cast<int4*>(&Asm[r * 64 + ((c16 * 8) ^ ((r & 7) << 3))]) = av;
        }
#pragma unroll
        for (int p = 0; p < 8; ++p) {
            const int s = t + 512 * p;
            const int r = s >> 3, c16 = s & 7;
            *reinterpret_cast<int4*>(&Bsm[r * 64 + ((c16 * 8) ^ ((r & 7) << 3))]) = bv[p];
        }
        __syncthreads();
#pragma unroll
        for (int kf = 0; kf < 2; ++kf) {
            const int kk = kf * 32 + fk;
            short8 af[2], bf[8];
#pragma unroll
            for (int mi = 0; mi < 2; ++mi) {
                const int row = wr * 32 + mi * 16 + frow;
                af[mi] = *reinterpret_cast<const short8*>(&Asm[row * 64 + (kk ^ ((row & 7) << 3))]);
            }
#pragma unroll
            for (int ni = 0; ni < 8; ++ni) {
                const int row = wc * 128 + ni * 16 + frow;
                bf[ni] = *reinterpret_cast<const short8*>(&Bsm[row * 64 + (kk ^ ((row & 7) << 3))]);
            }
#pragma unroll
            for (int mi = 0; mi < 2; ++mi)
#pragma unroll
                for (int ni = 0; ni < 8; ++ni)
                    acc[mi][ni] = __builtin_amdgcn_mfma_f32_16x16x32_bf16(af[mi], bf[ni], acc[mi][ni], 0, 0, 0);
        }
    }

    // ---- epilogue: +bias
#pragma unroll
    for (int ni = 0; ni < 8; ++ni) {
        const float bb = rbias[wc * 128 + ni * 16 + frow];
#pragma unroll
        for (int mi = 0; mi < 2; ++mi)
#pragma unroll
            for (int r_ = 0; r_ < 4; ++r_) acc[mi][ni][r_] += bb;
    }
    // per-row partials over this wave's 128 cols
#pragma unroll
    for (int mi = 0; mi < 2; ++mi)
#pragma unroll
        for (int r_ = 0; r_ < 4; ++r_) {
            float s = 0.f, q = 0.f;
#pragma unroll
            for (int ni = 0; ni < 8; ++ni) { const float v = acc[mi][ni][r_]; s += v; q += v * v; }
#pragma unroll
            for (int m = 8; m; m >>= 1) { s += __shfl_xor(s, m); q += __shfl_xor(q, m); }
            if (frow == 0) {
                const int row = wr * 32 + mi * 16 + (l >> 4) * 4 + r_;
                psum[row][wc] = s; psq[row][wc] = q;
            }
        }
    __syncthreads();   // also guarantees all Bsm frag reads are done
    if (t < 64) {
        const float s = psum[t][0] + psum[t][1] + psum[t][2] + psum[t][3];
        const float q = psq[t][0] + psq[t][1] + psq[t][2] + psq[t][3];
        const float m = s * (1.0f / Oo);
        muA[t] = m;
        rsA[t] = rsqrtf(q * (1.0f / Oo) - m * m + LN_EPS);
    }
    __syncthreads();

    // normalize + transpose via per-wave LDS patch (16 o x 32 n, pad 33), coalesced store
    float* ldsT = reinterpret_cast<float*>(Bsm) + w * (16 * 33);
#pragma unroll
    for (int ni = 0; ni < 8; ++ni) {
        const int o = wc * 128 + ni * 16 + frow;
        const float wv = nw[o], bv_ = nb[o];
#pragma unroll
        for (int mi = 0; mi < 2; ++mi)
#pragma unroll
            for (int r_ = 0; r_ < 4; ++r_) {
                const int nl = mi * 16 + (l >> 4) * 4 + r_;        // 0..31 within wave
                const int row = wr * 32 + nl;
                ldsT[frow * 33 + nl] = (acc[mi][ni][r_] - muA[row]) * rsA[row] * wv + bv_;
            }
#pragma unroll
        for (int p = 0; p < 8; ++p) {
            const int o_loc = p * 2 + (l >> 5);
            const float v = ldsT[o_loc * 33 + (l & 31)];
            const int o_g = wc * 128 + ni * 16 + o_loc;
            out[((long long)(b * Oo + o_g)) * Nn + n0 + wr * 32 + (l & 31)] = v;
        }
    }
}

extern "C" void kernel_launch(void* const* d_in, const int* in_sizes, int n_in,
                              void* d_out, int out_size, void* d_ws, size_t ws_size,
                              hipStream_t stream) {
    (void)in_sizes; (void)n_in; (void)out_size; (void)ws_size;
    const float* x1    = (const float*)d_in[0];
    const float* x2    = (const float*)d_in[1];
    const float* n1w   = (const float*)d_in[2];
    const float* n1b   = (const float*)d_in[3];
    const float* rw    = (const float*)d_in[4];
    const float* rbias = (const float*)d_in[5];
    const float* n2w   = (const float*)d_in[6];
    const float* n2b   = (const float*)d_in[7];
    const float* aw    = (const float*)d_in[8];
    float* out = (float*)d_out;

    // d_out doubles as scratch for KexpT/VT (dead before k_rpln's final overwrite).
    u16* KexpT = (u16*)d_out;
    u16* VT    = KexpT + (size_t)Bb * Nn * Cc;

    float* ws = (float*)d_ws;
    size_t off = 0;
    u16*   Qexp   = (u16*)(ws + off); off += (size_t)Bb * Nn * Cc / 2;  //  9,437,184 f32 slots
    float* ctxp   = ws + off; off += (size_t)KS2 * Bb * Cc * Cc;        //  4,194,304
    float* ctx    = ws + off; off += (size_t)Bb * Cc * Cc;              //    524,288
    float* Ac     = ws + off; off += (size_t)Bb * Cc * Cc;              //    524,288
    u16*   WAb16  = (u16*)(ws + off); off += (size_t)Bb * Oo * Cc / 2;  //    524,288
    float* pS     = ws + off; off += (size_t)Bb * 144 * Cc;             //    294,912
    float* colS   = ws + off; off += (size_t)Bb * Cc;
    float* x1mu   = ws + off; off += (size_t)Bb * Nn;
    float* x1rs   = ws + off; off += (size_t)Bb * Nn;
    float* x2mu   = ws + off; off += (size_t)Bb * Nn;
    float* x2rs   = ws + off; off += (size_t)Bb * Nn;

    k_stat<<<dim3(Bb * Nn / 4, 2), 256, 0, stream>>>(x1, x2, x1mu, x1rs, x2mu, x2rs);
    k_ln<<<dim3(Bb * Nn / 4), 256, 0, stream>>>(x2, n1w, n1b, Qexp);
    k_T<<<dim3(144, 4, Bb), 256, 0, stream>>>(x2, x2mu, x2rs, n1w, n1b, KexpT, pS, 1);
    k_T<<<dim3(144, 4, Bb), 256, 0, stream>>>(x1, x1mu, x1rs, n1w, n1b, VT, pS, 0);
    k_colcomb<<<dim3(Bb), 256, 0, stream>>>(pS, colS);
    k_mm_bf16<<<dim3(4, KS2, Bb), 256, 0, stream>>>(
        KexpT, VT, ctxp,
        Nn, Nn, Cc,
        (long long)Cc * Nn, (long long)Cc * Nn, (long long)Cc * Cc,
        Nn / KS2, (long long)Bb * Cc * Cc,
        Cc / 128, (Nn / KS2) / 64);
    k_ctxred<<<dim3(512), 256, 0, stream>>>(ctxp, colS, ctx);
    k_rank<<<dim3(Cc, Bb), 256, 0, stream>>>(ctx, aw, Ac);
    k_wa<<<dim3(32, Bb), 256, 0, stream>>>(rw, Ac, WAb16);
    k_rpln<<<dim3(144, 1, Bb), 512, 0, stream>>>(Qexp, WAb16, rbias, n2w, n2b, out);
}

// Round 5
// 348.766 us; speedup vs baseline: 1.7762x; 1.0120x over previous
//
#include <hip/hip_runtime.h>
#include <math.h>

typedef __attribute__((ext_vector_type(8))) short short8;
typedef __attribute__((ext_vector_type(4))) float f32x4;
typedef unsigned short u16;

constexpr int Bb = 8;
constexpr int Nn = 9216;   // 96*96
constexpr int Cc = 256;    // = D
constexpr int Oo = 512;    // 2C
constexpr float LN_EPS = 1e-5f;
constexpr int KS2 = 8;     // ctx GEMM split-K chunks (9216 = 8*1152)

static __device__ __forceinline__ u16 f2bf(float f) {
    unsigned u = __builtin_bit_cast(unsigned, f);
    u += 0x7fffu + ((u >> 16) & 1u);   // RNE
    return (u16)(u >> 16);
}
static __device__ __forceinline__ float bf2f(u16 u) {
    return __builtin_bit_cast(float, (unsigned)u << 16);
}

// ---------------- K0: per-row mean/rstd of x1 only (x2 stats come from k_ln)
__global__ __launch_bounds__(256) void k_stat(const float* __restrict__ x1,
                                              float* __restrict__ x1mu,
                                              float* __restrict__ x1rs) {
    const int lane = threadIdx.x & 63;
    const long long row = (long long)blockIdx.x * 4 + (threadIdx.x >> 6);
    const float4 v = reinterpret_cast<const float4*>(x1)[row * 64 + lane];
    float s = v.x + v.y + v.z + v.w;
    float q = v.x * v.x + v.y * v.y + v.z * v.z + v.w * v.w;
#pragma unroll
    for (int m = 32; m; m >>= 1) { s += __shfl_xor(s, m); q += __shfl_xor(q, m); }
    const float mu = s * (1.0f / Cc);
    const float rstd = rsqrtf(q * (1.0f / Cc) - mu * mu + LN_EPS);
    if (lane == 0) { x1mu[row] = mu; x1rs[row] = rstd; }
}

// ---------------- K1: LN(x2) -> row-softmax exp -> Qexp (bf16) + x2 stats out
__global__ __launch_bounds__(256) void k_ln(const float* __restrict__ x2,
                                            const float* __restrict__ nw,
                                            const float* __restrict__ nb,
                                            u16* __restrict__ Qexp,
                                            float* __restrict__ x2mu,
                                            float* __restrict__ x2rs) {
    const int lane = threadIdx.x & 63;
    const long long row = (long long)blockIdx.x * 4 + (threadIdx.x >> 6);

    const float4 v = reinterpret_cast<const float4*>(x2)[row * 64 + lane];
    float s = v.x + v.y + v.z + v.w;
    float q = v.x * v.x + v.y * v.y + v.z * v.z + v.w * v.w;
#pragma unroll
    for (int m = 32; m; m >>= 1) { s += __shfl_xor(s, m); q += __shfl_xor(q, m); }
    const float mu = s * (1.0f / Cc);
    const float rstd = rsqrtf(q * (1.0f / Cc) - mu * mu + LN_EPS);
    if (lane == 0) { x2mu[row] = mu; x2rs[row] = rstd; }

    const float4 w4 = reinterpret_cast<const float4*>(nw)[lane];
    const float4 b4 = reinterpret_cast<const float4*>(nb)[lane];
    float4 y;
    y.x = (v.x - mu) * rstd * w4.x + b4.x;
    y.y = (v.y - mu) * rstd * w4.y + b4.y;
    y.z = (v.z - mu) * rstd * w4.z + b4.z;
    y.w = (v.w - mu) * rstd * w4.w + b4.w;

    float mx = fmaxf(fmaxf(y.x, y.y), fmaxf(y.z, y.w));
#pragma unroll
    for (int m = 32; m; m >>= 1) mx = fmaxf(mx, __shfl_xor(mx, m));
    float es = __expf(y.x - mx) + __expf(y.y - mx) + __expf(y.z - mx) + __expf(y.w - mx);
#pragma unroll
    for (int m = 32; m; m >>= 1) es += __shfl_xor(es, m);
    const float inv = 1.0f / es;
    const u16 q0 = f2bf(__expf(y.x - mx) * inv);
    const u16 q1 = f2bf(__expf(y.y - mx) * inv);
    const u16 q2 = f2bf(__expf(y.z - mx) * inv);
    const u16 q3 = f2bf(__expf(y.w - mx) * inv);
    int2 pk;
    pk.x = (int)((unsigned)q0 | ((unsigned)q1 << 16));
    pk.y = (int)((unsigned)q2 | ((unsigned)q3 << 16));
    *reinterpret_cast<int2*>(Qexp + row * Cc + lane * 4) = pk;
}

// ---------------- K2: tiled LN(+exp) transpose: src [b][n][d] f32 -> dstT [b][d][n] bf16.
__global__ __launch_bounds__(256) void k_T(const float* __restrict__ src,
                                           const float* __restrict__ mu,
                                           const float* __restrict__ rs,
                                           const float* __restrict__ lnw,
                                           const float* __restrict__ lnb,
                                           u16* __restrict__ dstT,
                                           float* __restrict__ pS,
                                           int doExp) {
    __shared__ u16 tile[64][72];   // [d][n], pad 72 u16 = 144 B rows (16B aligned)
    const int b = blockIdx.z, dt = blockIdx.y, nc = blockIdx.x;
    const int d0 = dt * 64, n0 = nc * 64;
    const int t = threadIdx.x;
    const int ln_ = t >> 4;        // 0..15  n-row within pass
    const int dc = t & 15;         // d float4 group
    const float4 w4 = *reinterpret_cast<const float4*>(lnw + d0 + dc * 4);
    const float4 b4 = *reinterpret_cast<const float4*>(lnb + d0 + dc * 4);
#pragma unroll
    for (int p = 0; p < 4; ++p) {
        const int nl = p * 16 + ln_;
        const long long row = (long long)b * Nn + n0 + nl;
        const float4 v = *reinterpret_cast<const float4*>(src + row * Cc + d0 + dc * 4);
        const float m_ = mu[row], r_ = rs[row];
        float y0 = (v.x - m_) * r_ * w4.x + b4.x;
        float y1 = (v.y - m_) * r_ * w4.y + b4.y;
        float y2 = (v.z - m_) * r_ * w4.z + b4.z;
        float y3 = (v.w - m_) * r_ * w4.w + b4.w;
        if (doExp) { y0 = __expf(y0); y1 = __expf(y1); y2 = __expf(y2); y3 = __expf(y3); }
        tile[dc * 4 + 0][nl] = f2bf(y0);
        tile[dc * 4 + 1][nl] = f2bf(y1);
        tile[dc * 4 + 2][nl] = f2bf(y2);
        tile[dc * 4 + 3][nl] = f2bf(y3);
    }
    __syncthreads();
#pragma unroll
    for (int p = 0; p < 2; ++p) {
        const int r = p * 32 + (t >> 3);
        const int c = (t & 7) * 8;
        const int4 v = *reinterpret_cast<const int4*>(&tile[r][c]);
        *reinterpret_cast<int4*>(dstT + ((long long)(b * Cc + d0 + r)) * Nn + n0 + c) = v;
    }
    if (doExp) {
        const int d = t >> 2, part = t & 3;
        const int4 u0 = *reinterpret_cast<const int4*>(&tile[d][part * 16]);
        const int4 u1 = *reinterpret_cast<const int4*>(&tile[d][part * 16 + 8]);
        float s = 0.f;
        const int us[8] = {u0.x, u0.y, u0.z, u0.w, u1.x, u1.y, u1.z, u1.w};
#pragma unroll
        for (int i = 0; i < 8; ++i) {
            s += bf2f((u16)(us[i] & 0xffff));
            s += bf2f((u16)(((unsigned)us[i]) >> 16));
        }
        s += __shfl_xor(s, 1);
        s += __shfl_xor(s, 2);
        if (part == 0) pS[((long long)b * 144 + nc) * Cc + d0 + d] = s;
    }
}

// ---------------- K2b: colS[b][d] = sum over 144 chunks
__global__ __launch_bounds__(256) void k_colcomb(const float* __restrict__ pS,
                                                 float* __restrict__ colS) {
    const int d = threadIdx.x, b = blockIdx.x;
    float s = 0.f;
    for (int c = 0; c < 144; ++c) s += pS[((long long)b * 144 + c) * Cc + d];
    colS[b * Cc + d] = s;
}

// ---------------- K6: bf16 MFMA GEMM (ctx).  C[m][n] = sum_k A[m][k] * Bt[n][k]
__global__ __launch_bounds__(256) void k_mm_bf16(const u16* __restrict__ A,
                                                 const u16* __restrict__ Bt,
                                                 float* __restrict__ C,
                                                 int lda, int ldb, int ldc,
                                                 long long sAb, long long sBb, long long sCb,
                                                 int kChunk, long long sCk,
                                                 int tilesN, int kIters) {
    __shared__ alignas(16) u16 Asm[128 * 64];
    __shared__ alignas(16) u16 Bsm[128 * 64];
    const int t = threadIdx.x;
    const int b = blockIdx.z, kc = blockIdx.y;
    const int tm = blockIdx.x / tilesN, tn = blockIdx.x % tilesN;
    const int m0 = tm * 128, n0 = tn * 128;
    const u16* Ag = A + b * sAb + (long long)kc * kChunk;
    const u16* Bg = Bt + b * sBb + (long long)kc * kChunk;
    float* Cg = C + b * sCb + (long long)kc * sCk;

    const int l = t & 63, w = t >> 6;
    const int wr = w >> 1, wc = w & 1;
    const int frow = l & 15, fk = (l >> 4) << 3;

    f32x4 acc[4][4] = {};

    for (int kt = 0; kt < kIters; ++kt) {
        const int k0 = kt * 64;
        int4 av[4], bv[4];
#pragma unroll
        for (int i = 0; i < 4; ++i) {
            const int s = t + 256 * i;
            const int r = s >> 3, c16 = s & 7;
            av[i] = *reinterpret_cast<const int4*>(Ag + (long long)(m0 + r) * lda + k0 + c16 * 8);
            bv[i] = *reinterpret_cast<const int4*>(Bg + (long long)(n0 + r) * ldb + k0 + c16 * 8);
        }
        __syncthreads();
#pragma unroll
        for (int i = 0; i < 4; ++i) {
            const int s = t + 256 * i;
            const int r = s >> 3, c16 = s & 7;
            const int idx = r * 64 + ((c16 * 8) ^ ((r & 7) << 3));
            *reinterpret_cast<int4*>(&Asm[idx]) = av[i];
            *reinterpret_cast<int4*>(&Bsm[idx]) = bv[i];
        }
        __syncthreads();
#pragma unroll
        for (int kf = 0; kf < 2; ++kf) {
            short8 af[4], bf[4];
            const int kk = kf * 32 + fk;
#pragma unroll
            for (int mi = 0; mi < 4; ++mi) {
                const int row = wr * 64 + mi * 16 + frow;
                af[mi] = *reinterpret_cast<const short8*>(&Asm[row * 64 + (kk ^ ((row & 7) << 3))]);
            }
#pragma unroll
            for (int ni = 0; ni < 4; ++ni) {
                const int row = wc * 64 + ni * 16 + frow;
                bf[ni] = *reinterpret_cast<const short8*>(&Bsm[row * 64 + (kk ^ ((row & 7) << 3))]);
            }
#pragma unroll
            for (int mi = 0; mi < 4; ++mi)
#pragma unroll
                for (int ni = 0; ni < 4; ++ni)
                    acc[mi][ni] = __builtin_amdgcn_mfma_f32_16x16x32_bf16(af[mi], bf[ni], acc[mi][ni], 0, 0, 0);
        }
    }

    const int crow0 = (l >> 4) * 4, ccol = l & 15;
#pragma unroll
    for (int mi = 0; mi < 4; ++mi) {
#pragma unroll
        for (int ni = 0; ni < 4; ++ni) {
            const int row = m0 + wr * 64 + mi * 16 + crow0;
            const int col = n0 + wc * 64 + ni * 16 + ccol;
#pragma unroll
            for (int r_ = 0; r_ < 4; ++r_)
                Cg[(long long)(row + r_) * ldc + col] = acc[mi][ni][r_];
        }
    }
}

// ---------------- K3b: split-K reduction + 1/colS row scale
__global__ __launch_bounds__(256) void k_ctxred(const float* __restrict__ ctxp,
                                                const float* __restrict__ colS,
                                                float* __restrict__ ctx) {
    const long long i4 = ((long long)blockIdx.x * 256 + threadIdx.x) * 4;
    float4 s = make_float4(0.f, 0.f, 0.f, 0.f);
    for (int kc = 0; kc < KS2; ++kc) {
        const float4 v = *reinterpret_cast<const float4*>(ctxp + (long long)kc * (Bb * Cc * Cc) + i4);
        s.x += v.x; s.y += v.y; s.z += v.z; s.w += v.w;
    }
    const int b = (int)(i4 >> 16);
    const int d = ((int)(i4 >> 8)) & 255;
    const float inv = 1.0f / colS[b * Cc + d];
    s.x *= inv; s.y *= inv; s.z *= inv; s.w *= inv;
    *reinterpret_cast<float4*>(ctx + i4) = s;
}

// ---------------- K4: rank + combined top-k softmax coefficients. block per (b,d) row.
__global__ __launch_bounds__(256) void k_rank(const float* __restrict__ ctx,
                                              const float* __restrict__ aw,
                                              float* __restrict__ Ac) {
    __shared__ float row[256];
    __shared__ float red[256];
    const int d = blockIdx.x, b = blockIdx.y, e = threadIdx.x;
    const float c = ctx[((long long)(b * Cc + d)) * Cc + e];
    row[e] = c;
    __syncthreads();
    int p = 0;
    for (int j = 0; j < 256; ++j) {
        const float cj = row[j];
        p += (cj > c) || (cj == c && j < e);  // stable top_k rank (0-based)
    }
    red[e] = c; __syncthreads();
    for (int s_ = 128; s_; s_ >>= 1) { if (e < s_) red[e] = fmaxf(red[e], red[e + s_]); __syncthreads(); }
    const float m = red[0];
    const float ex = __expf(c - m);
    const int kks[4] = {128, 170, 192, 204};
    float Zv[4];
#pragma unroll
    for (int i = 0; i < 4; ++i) {
        __syncthreads();
        red[e] = (p < kks[i]) ? ex : 0.0f;
        __syncthreads();
        for (int s_ = 128; s_; s_ >>= 1) { if (e < s_) red[e] += red[e + s_]; __syncthreads(); }
        Zv[i] = red[0];
    }
    float wsum = 0.0f;
#pragma unroll
    for (int i = 0; i < 4; ++i)
        if (p < kks[i]) wsum += aw[i] / Zv[i];
    Ac[((long long)(b * Cc + d)) * Cc + e] = ex * wsum;
}

// ---------------- K5: WA[b,o,e] = sum_d W[o,d] * A[b,d,e] -> bf16. grid (32, 8), block 256.
__global__ __launch_bounds__(256) void k_wa(const float* __restrict__ W,
                                            const float* __restrict__ Ac,
                                            u16* __restrict__ WAb16) {
    __shared__ float As[16][64], Bs[16][64];
    const int b = blockIdx.y;
    const int o0 = (blockIdx.x >> 2) * 64, e0 = (blockIdx.x & 3) * 64;
    const int t = threadIdx.x, tx = t & 15, ty = t >> 4;
    const int a_oo = t >> 2, a_k4 = (t & 3) * 4;
    const int b_kk = t >> 4, b_e4 = (t & 15) * 4;
    float acc[4][4] = {{0.f}};
    for (int kd = 0; kd < 256; kd += 16) {
        const float4 wv = *reinterpret_cast<const float4*>(W + (o0 + a_oo) * Cc + kd + a_k4);
        const float4 av = *reinterpret_cast<const float4*>(Ac + ((long long)(b * Cc + kd + b_kk)) * Cc + e0 + b_e4);
        __syncthreads();
        As[a_k4 + 0][a_oo] = wv.x; As[a_k4 + 1][a_oo] = wv.y;
        As[a_k4 + 2][a_oo] = wv.z; As[a_k4 + 3][a_oo] = wv.w;
        *reinterpret_cast<float4*>(&Bs[b_kk][b_e4]) = av;
        __syncthreads();
#pragma unroll
        for (int kk = 0; kk < 16; ++kk) {
            const float4 a4 = *reinterpret_cast<const float4*>(&As[kk][ty * 4]);
            const float4 b4 = *reinterpret_cast<const float4*>(&Bs[kk][tx * 4]);
            const float aa[4] = {a4.x, a4.y, a4.z, a4.w};
            const float bb[4] = {b4.x, b4.y, b4.z, b4.w};
#pragma unroll
            for (int i = 0; i < 4; ++i)
#pragma unroll
                for (int j = 0; j < 4; ++j) acc[i][j] = fmaf(aa[i], bb[j], acc[i][j]);
        }
    }
#pragma unroll
    for (int i = 0; i < 4; ++i) {
        int2 pk;
        pk.x = (int)((unsigned)f2bf(acc[i][0]) | ((unsigned)f2bf(acc[i][1]) << 16));
        pk.y = (int)((unsigned)f2bf(acc[i][2]) | ((unsigned)f2bf(acc[i][3]) << 16));
        *reinterpret_cast<int2*>(WAb16 + ((long long)(b * Oo + o0 + ty * 4 + i)) * Cc + e0 + tx * 4) = pk;
    }
}

// ---------------- K7: fused reprojection GEMM + bias + LN(512) + transposed store.
// grid (144, 1, 8), block 512 (8 waves, 2M x 4N). Tile: 64 n-rows x 512 o x K=256.
// Epilogue v2: wr-pair-shared 16o x 64n patches -> 256-B contiguous wave stores.
__global__ __launch_bounds__(512) void k_rpln(const u16* __restrict__ Qexp,
                                              const u16* __restrict__ WAb16,
                                              const float* __restrict__ rbias,
                                              const float* __restrict__ nw,
                                              const float* __restrict__ nb,
                                              float* __restrict__ out) {
    __shared__ alignas(16) unsigned char smemRaw[73728];  // Asm 8K + Bsm 64K; reused as patches
    u16* Asm = reinterpret_cast<u16*>(smemRaw);
    u16* Bsm = reinterpret_cast<u16*>(smemRaw + 8192);
    float (*patch)[16][65] = reinterpret_cast<float (*)[16][65]>(smemRaw);  // [wc][o][n]
    __shared__ float psum[64][4], psq[64][4];
    __shared__ float muA[64], rsA[64];

    const int t = threadIdx.x;
    const int b = blockIdx.z;
    const int n0 = blockIdx.x * 64;
    const int l = t & 63, w = t >> 6;
    const int wr = w >> 2, wc = w & 3;          // 2 (M) x 4 (N) waves
    const int frow = l & 15, fk = (l >> 4) << 3;

    f32x4 acc[2][8] = {};

    const u16* Ag = Qexp + ((long long)b * Nn + n0) * Cc;
    const u16* Bg = WAb16 + (long long)b * Oo * Cc;

    for (int kt = 0; kt < 4; ++kt) {
        const int k0 = kt * 64;
        int4 av;
        {
            const int r = t >> 3, c16 = t & 7;
            av = *reinterpret_cast<const int4*>(Ag + (long long)r * Cc + k0 + c16 * 8);
        }
        int4 bv[8];
#pragma unroll
        for (int p = 0; p < 8; ++p) {
            const int s = t + 512 * p;
            const int r = s >> 3, c16 = s & 7;
            bv[p] = *reinterpret_cast<const int4*>(Bg + (long long)r * Cc + k0 + c16 * 8);
        }
        __syncthreads();
        {
            const int r = t >> 3, c16 = t & 7;
            *reinterpret_cast<int4*>(&Asm[r * 64 + ((c16 * 8) ^ ((r & 7) << 3))]) = av;
        }
#pragma unroll
        for (int p = 0; p < 8; ++p) {
            const int s = t + 512 * p;
            const int r = s >> 3, c16 = s & 7;
            *reinterpret_cast<int4*>(&Bsm[r * 64 + ((c16 * 8) ^ ((r & 7) << 3))]) = bv[p];
        }
        __syncthreads();
#pragma unroll
        for (int kf = 0; kf < 2; ++kf) {
            const int kk = kf * 32 + fk;
            short8 af[2], bf[8];
#pragma unroll
            for (int mi = 0; mi < 2; ++mi) {
                const int row = wr * 32 + mi * 16 + frow;
                af[mi] = *reinterpret_cast<const short8*>(&Asm[row * 64 + (kk ^ ((row & 7) << 3))]);
            }
#pragma unroll
            for (int ni = 0; ni < 8; ++ni) {
                const int row = wc * 128 + ni * 16 + frow;
                bf[ni] = *reinterpret_cast<const short8*>(&Bsm[row * 64 + (kk ^ ((row & 7) << 3))]);
            }
#pragma unroll
            for (int mi = 0; mi < 2; ++mi)
#pragma unroll
                for (int ni = 0; ni < 8; ++ni)
                    acc[mi][ni] = __builtin_amdgcn_mfma_f32_16x16x32_bf16(af[mi], bf[ni], acc[mi][ni], 0, 0, 0);
        }
    }

    // ---- epilogue: +bias
#pragma unroll
    for (int ni = 0; ni < 8; ++ni) {
        const float bb = rbias[wc * 128 + ni * 16 + frow];
#pragma unroll
        for (int mi = 0; mi < 2; ++mi)
#pragma unroll
            for (int r_ = 0; r_ < 4; ++r_) acc[mi][ni][r_] += bb;
    }
    // per-row partials over this wave's 128 cols
#pragma unroll
    for (int mi = 0; mi < 2; ++mi)
#pragma unroll
        for (int r_ = 0; r_ < 4; ++r_) {
            float s = 0.f, q = 0.f;
#pragma unroll
            for (int ni = 0; ni < 8; ++ni) { const float v = acc[mi][ni][r_]; s += v; q += v * v; }
#pragma unroll
            for (int m = 8; m; m >>= 1) { s += __shfl_xor(s, m); q += __shfl_xor(q, m); }
            if (frow == 0) {
                const int row = wr * 32 + mi * 16 + (l >> 4) * 4 + r_;
                psum[row][wc] = s; psq[row][wc] = q;
            }
        }
    __syncthreads();   // also ensures all Asm/Bsm fragment reads are done
    if (t < 64) {
        const float s = psum[t][0] + psum[t][1] + psum[t][2] + psum[t][3];
        const float q = psq[t][0] + psq[t][1] + psq[t][2] + psq[t][3];
        const float m = s * (1.0f / Oo);
        muA[t] = m;
        rsA[t] = rsqrtf(q * (1.0f / Oo) - m * m + LN_EPS);
    }
    __syncthreads();

    // preload this lane's LN gamma/beta for its 8 o values
    float nwv[8], nbv[8];
#pragma unroll
    for (int ni = 0; ni < 8; ++ni) {
        const int o = wc * 128 + ni * 16 + frow;
        nwv[ni] = nw[o]; nbv[ni] = nb[o];
    }

    // per ni: both wr-waves of a wc fill patch[wc] (16 o x 64 n), then store
    // one o-row per wave-instruction: 64 lanes x 4B = 256-B contiguous segment.
    const int hi = l >> 4;
#pragma unroll
    for (int ni = 0; ni < 8; ++ni) {
#pragma unroll
        for (int mi = 0; mi < 2; ++mi)
#pragma unroll
            for (int r_ = 0; r_ < 4; ++r_) {
                const int nl = wr * 32 + mi * 16 + hi * 4 + r_;   // 0..63
                patch[wc][frow][nl] = (acc[mi][ni][r_] - muA[nl]) * rsA[nl] * nwv[ni] + nbv[ni];
            }
        __syncthreads();
#pragma unroll
        for (int p = 0; p < 8; ++p) {
            const int o_loc = wr * 8 + p;                          // 0..15
            const int o_g = wc * 128 + ni * 16 + o_loc;
            out[((long long)(b * Oo + o_g)) * Nn + n0 + l] = patch[wc][o_loc][l];
        }
        __syncthreads();
    }
}

extern "C" void kernel_launch(void* const* d_in, const int* in_sizes, int n_in,
                              void* d_out, int out_size, void* d_ws, size_t ws_size,
                              hipStream_t stream) {
    (void)in_sizes; (void)n_in; (void)out_size; (void)ws_size;
    const float* x1    = (const float*)d_in[0];
    const float* x2    = (const float*)d_in[1];
    const float* n1w   = (const float*)d_in[2];
    const float* n1b   = (const float*)d_in[3];
    const float* rw    = (const float*)d_in[4];
    const float* rbias = (const float*)d_in[5];
    const float* n2w   = (const float*)d_in[6];
    const float* n2b   = (const float*)d_in[7];
    const float* aw    = (const float*)d_in[8];
    float* out = (float*)d_out;

    // d_out doubles as scratch for KexpT/VT (dead before k_rpln's final overwrite).
    u16* KexpT = (u16*)d_out;
    u16* VT    = KexpT + (size_t)Bb * Nn * Cc;

    float* ws = (float*)d_ws;
    size_t off = 0;
    u16*   Qexp   = (u16*)(ws + off); off += (size_t)Bb * Nn * Cc / 2;
    float* ctxp   = ws + off; off += (size_t)KS2 * Bb * Cc * Cc;
    float* ctx    = ws + off; off += (size_t)Bb * Cc * Cc;
    float* Ac     = ws + off; off += (size_t)Bb * Cc * Cc;
    u16*   WAb16  = (u16*)(ws + off); off += (size_t)Bb * Oo * Cc / 2;
    float* pS     = ws + off; off += (size_t)Bb * 144 * Cc;
    float* colS   = ws + off; off += (size_t)Bb * Cc;
    float* x1mu   = ws + off; off += (size_t)Bb * Nn;
    float* x1rs   = ws + off; off += (size_t)Bb * Nn;
    float* x2mu   = ws + off; off += (size_t)Bb * Nn;
    float* x2rs   = ws + off; off += (size_t)Bb * Nn;

    k_stat<<<dim3(Bb * Nn / 4), 256, 0, stream>>>(x1, x1mu, x1rs);
    k_ln<<<dim3(Bb * Nn / 4), 256, 0, stream>>>(x2, n1w, n1b, Qexp, x2mu, x2rs);
    k_T<<<dim3(144, 4, Bb), 256, 0, stream>>>(x2, x2mu, x2rs, n1w, n1b, KexpT, pS, 1);
    k_T<<<dim3(144, 4, Bb), 256, 0, stream>>>(x1, x1mu, x1rs, n1w, n1b, VT, pS, 0);
    k_colcomb<<<dim3(Bb), 256, 0, stream>>>(pS, colS);
    k_mm_bf16<<<dim3(4, KS2, Bb), 256, 0, stream>>>(
        KexpT, VT, ctxp,
        Nn, Nn, Cc,
        (long long)Cc * Nn, (long long)Cc * Nn, (long long)Cc * Cc,
        Nn / KS2, (long long)Bb * Cc * Cc,
        Cc / 128, (Nn / KS2) / 64);
    k_ctxred<<<dim3(512), 256, 0, stream>>>(ctxp, colS, ctx);
    k_rank<<<dim3(Cc, Bb), 256, 0, stream>>>(ctx, aw, Ac);
    k_wa<<<dim3(32, Bb), 256, 0, stream>>>(rw, Ac, WAb16);
    k_rpln<<<dim3(144, 1, Bb), 512, 0, stream>>>(Qexp, WAb16, rbias, n2w, n2b, out);
}

// Round 6
// 322.531 us; speedup vs baseline: 1.9207x; 1.0813x over previous
//
#include <hip/hip_runtime.h>
#include <math.h>

typedef __attribute__((ext_vector_type(8))) short short8;
typedef __attribute__((ext_vector_type(4))) float f32x4;
typedef unsigned short u16;

constexpr int Bb = 8;
constexpr int Nn = 9216;   // 96*96
constexpr int Cc = 256;    // = D
constexpr int Oo = 512;    // 2C
constexpr float LN_EPS = 1e-5f;
constexpr int KS2 = 8;     // ctx GEMM split-K chunks (9216 = 8*1152)

static __device__ __forceinline__ u16 f2bf(float f) {
    unsigned u = __builtin_bit_cast(unsigned, f);
    u += 0x7fffu + ((u >> 16) & 1u);   // RNE
    return (u16)(u >> 16);
}
static __device__ __forceinline__ float bf2f(u16 u) {
    return __builtin_bit_cast(float, (unsigned)u << 16);
}

// ---------------- K0: per-row mean/rstd of x1 only (x2 stats come from k_ln)
__global__ __launch_bounds__(256) void k_stat(const float* __restrict__ x1,
                                              float* __restrict__ x1mu,
                                              float* __restrict__ x1rs) {
    const int lane = threadIdx.x & 63;
    const long long row = (long long)blockIdx.x * 4 + (threadIdx.x >> 6);
    const float4 v = reinterpret_cast<const float4*>(x1)[row * 64 + lane];
    float s = v.x + v.y + v.z + v.w;
    float q = v.x * v.x + v.y * v.y + v.z * v.z + v.w * v.w;
#pragma unroll
    for (int m = 32; m; m >>= 1) { s += __shfl_xor(s, m); q += __shfl_xor(q, m); }
    const float mu = s * (1.0f / Cc);
    const float rstd = rsqrtf(q * (1.0f / Cc) - mu * mu + LN_EPS);
    if (lane == 0) { x1mu[row] = mu; x1rs[row] = rstd; }
}

// ---------------- K1: LN(x2) -> row-softmax exp -> Qexp (bf16) + x2 stats out
__global__ __launch_bounds__(256) void k_ln(const float* __restrict__ x2,
                                            const float* __restrict__ nw,
                                            const float* __restrict__ nb,
                                            u16* __restrict__ Qexp,
                                            float* __restrict__ x2mu,
                                            float* __restrict__ x2rs) {
    const int lane = threadIdx.x & 63;
    const long long row = (long long)blockIdx.x * 4 + (threadIdx.x >> 6);

    const float4 v = reinterpret_cast<const float4*>(x2)[row * 64 + lane];
    float s = v.x + v.y + v.z + v.w;
    float q = v.x * v.x + v.y * v.y + v.z * v.z + v.w * v.w;
#pragma unroll
    for (int m = 32; m; m >>= 1) { s += __shfl_xor(s, m); q += __shfl_xor(q, m); }
    const float mu = s * (1.0f / Cc);
    const float rstd = rsqrtf(q * (1.0f / Cc) - mu * mu + LN_EPS);
    if (lane == 0) { x2mu[row] = mu; x2rs[row] = rstd; }

    const float4 w4 = reinterpret_cast<const float4*>(nw)[lane];
    const float4 b4 = reinterpret_cast<const float4*>(nb)[lane];
    float4 y;
    y.x = (v.x - mu) * rstd * w4.x + b4.x;
    y.y = (v.y - mu) * rstd * w4.y + b4.y;
    y.z = (v.z - mu) * rstd * w4.z + b4.z;
    y.w = (v.w - mu) * rstd * w4.w + b4.w;

    float mx = fmaxf(fmaxf(y.x, y.y), fmaxf(y.z, y.w));
#pragma unroll
    for (int m = 32; m; m >>= 1) mx = fmaxf(mx, __shfl_xor(mx, m));
    float es = __expf(y.x - mx) + __expf(y.y - mx) + __expf(y.z - mx) + __expf(y.w - mx);
#pragma unroll
    for (int m = 32; m; m >>= 1) es += __shfl_xor(es, m);
    const float inv = 1.0f / es;
    const u16 q0 = f2bf(__expf(y.x - mx) * inv);
    const u16 q1 = f2bf(__expf(y.y - mx) * inv);
    const u16 q2 = f2bf(__expf(y.z - mx) * inv);
    const u16 q3 = f2bf(__expf(y.w - mx) * inv);
    int2 pk;
    pk.x = (int)((unsigned)q0 | ((unsigned)q1 << 16));
    pk.y = (int)((unsigned)q2 | ((unsigned)q3 << 16));
    *reinterpret_cast<int2*>(Qexp + row * Cc + lane * 4) = pk;
}

// ---------------- K2: tiled LN(+exp) transpose: src [b][n][d] f32 -> dstT [b][d][n] bf16.
__global__ __launch_bounds__(256) void k_T(const float* __restrict__ src,
                                           const float* __restrict__ mu,
                                           const float* __restrict__ rs,
                                           const float* __restrict__ lnw,
                                           const float* __restrict__ lnb,
                                           u16* __restrict__ dstT,
                                           float* __restrict__ pS,
                                           int doExp) {
    __shared__ u16 tile[64][72];   // [d][n], pad 72 u16 = 144 B rows (16B aligned)
    const int b = blockIdx.z, dt = blockIdx.y, nc = blockIdx.x;
    const int d0 = dt * 64, n0 = nc * 64;
    const int t = threadIdx.x;
    const int ln_ = t >> 4;        // 0..15  n-row within pass
    const int dc = t & 15;         // d float4 group
    const float4 w4 = *reinterpret_cast<const float4*>(lnw + d0 + dc * 4);
    const float4 b4 = *reinterpret_cast<const float4*>(lnb + d0 + dc * 4);
#pragma unroll
    for (int p = 0; p < 4; ++p) {
        const int nl = p * 16 + ln_;
        const long long row = (long long)b * Nn + n0 + nl;
        const float4 v = *reinterpret_cast<const float4*>(src + row * Cc + d0 + dc * 4);
        const float m_ = mu[row], r_ = rs[row];
        float y0 = (v.x - m_) * r_ * w4.x + b4.x;
        float y1 = (v.y - m_) * r_ * w4.y + b4.y;
        float y2 = (v.z - m_) * r_ * w4.z + b4.z;
        float y3 = (v.w - m_) * r_ * w4.w + b4.w;
        if (doExp) { y0 = __expf(y0); y1 = __expf(y1); y2 = __expf(y2); y3 = __expf(y3); }
        tile[dc * 4 + 0][nl] = f2bf(y0);
        tile[dc * 4 + 1][nl] = f2bf(y1);
        tile[dc * 4 + 2][nl] = f2bf(y2);
        tile[dc * 4 + 3][nl] = f2bf(y3);
    }
    __syncthreads();
#pragma unroll
    for (int p = 0; p < 2; ++p) {
        const int r = p * 32 + (t >> 3);
        const int c = (t & 7) * 8;
        const int4 v = *reinterpret_cast<const int4*>(&tile[r][c]);
        *reinterpret_cast<int4*>(dstT + ((long long)(b * Cc + d0 + r)) * Nn + n0 + c) = v;
    }
    if (doExp) {
        const int d = t >> 2, part = t & 3;
        const int4 u0 = *reinterpret_cast<const int4*>(&tile[d][part * 16]);
        const int4 u1 = *reinterpret_cast<const int4*>(&tile[d][part * 16 + 8]);
        float s = 0.f;
        const int us[8] = {u0.x, u0.y, u0.z, u0.w, u1.x, u1.y, u1.z, u1.w};
#pragma unroll
        for (int i = 0; i < 8; ++i) {
            s += bf2f((u16)(us[i] & 0xffff));
            s += bf2f((u16)(((unsigned)us[i]) >> 16));
        }
        s += __shfl_xor(s, 1);
        s += __shfl_xor(s, 2);
        if (part == 0) pS[((long long)b * 144 + nc) * Cc + d0 + d] = s;
    }
}

// ---------------- K2b: colS[b][d] = sum over 144 chunks
__global__ __launch_bounds__(256) void k_colcomb(const float* __restrict__ pS,
                                                 float* __restrict__ colS) {
    const int d = threadIdx.x, b = blockIdx.x;
    float s = 0.f;
    for (int c = 0; c < 144; ++c) s += pS[((long long)b * 144 + c) * Cc + d];
    colS[b * Cc + d] = s;
}

// ---------------- K6: bf16 MFMA GEMM (ctx).  C[m][n] = sum_k A[m][k] * Bt[n][k]
__global__ __launch_bounds__(256) void k_mm_bf16(const u16* __restrict__ A,
                                                 const u16* __restrict__ Bt,
                                                 float* __restrict__ C,
                                                 int lda, int ldb, int ldc,
                                                 long long sAb, long long sBb, long long sCb,
                                                 int kChunk, long long sCk,
                                                 int tilesN, int kIters) {
    __shared__ alignas(16) u16 Asm[128 * 64];
    __shared__ alignas(16) u16 Bsm[128 * 64];
    const int t = threadIdx.x;
    const int b = blockIdx.z, kc = blockIdx.y;
    const int tm = blockIdx.x / tilesN, tn = blockIdx.x % tilesN;
    const int m0 = tm * 128, n0 = tn * 128;
    const u16* Ag = A + b * sAb + (long long)kc * kChunk;
    const u16* Bg = Bt + b * sBb + (long long)kc * kChunk;
    float* Cg = C + b * sCb + (long long)kc * sCk;

    const int l = t & 63, w = t >> 6;
    const int wr = w >> 1, wc = w & 1;
    const int frow = l & 15, fk = (l >> 4) << 3;

    f32x4 acc[4][4] = {};

    for (int kt = 0; kt < kIters; ++kt) {
        const int k0 = kt * 64;
        int4 av[4], bv[4];
#pragma unroll
        for (int i = 0; i < 4; ++i) {
            const int s = t + 256 * i;
            const int r = s >> 3, c16 = s & 7;
            av[i] = *reinterpret_cast<const int4*>(Ag + (long long)(m0 + r) * lda + k0 + c16 * 8);
            bv[i] = *reinterpret_cast<const int4*>(Bg + (long long)(n0 + r) * ldb + k0 + c16 * 8);
        }
        __syncthreads();
#pragma unroll
        for (int i = 0; i < 4; ++i) {
            const int s = t + 256 * i;
            const int r = s >> 3, c16 = s & 7;
            const int idx = r * 64 + ((c16 * 8) ^ ((r & 7) << 3));
            *reinterpret_cast<int4*>(&Asm[idx]) = av[i];
            *reinterpret_cast<int4*>(&Bsm[idx]) = bv[i];
        }
        __syncthreads();
#pragma unroll
        for (int kf = 0; kf < 2; ++kf) {
            short8 af[4], bf[4];
            const int kk = kf * 32 + fk;
#pragma unroll
            for (int mi = 0; mi < 4; ++mi) {
                const int row = wr * 64 + mi * 16 + frow;
                af[mi] = *reinterpret_cast<const short8*>(&Asm[row * 64 + (kk ^ ((row & 7) << 3))]);
            }
#pragma unroll
            for (int ni = 0; ni < 4; ++ni) {
                const int row = wc * 64 + ni * 16 + frow;
                bf[ni] = *reinterpret_cast<const short8*>(&Bsm[row * 64 + (kk ^ ((row & 7) << 3))]);
            }
#pragma unroll
            for (int mi = 0; mi < 4; ++mi)
#pragma unroll
                for (int ni = 0; ni < 4; ++ni)
                    acc[mi][ni] = __builtin_amdgcn_mfma_f32_16x16x32_bf16(af[mi], bf[ni], acc[mi][ni], 0, 0, 0);
        }
    }

    const int crow0 = (l >> 4) * 4, ccol = l & 15;
#pragma unroll
    for (int mi = 0; mi < 4; ++mi) {
#pragma unroll
        for (int ni = 0; ni < 4; ++ni) {
            const int row = m0 + wr * 64 + mi * 16 + crow0;
            const int col = n0 + wc * 64 + ni * 16 + ccol;
#pragma unroll
            for (int r_ = 0; r_ < 4; ++r_)
                Cg[(long long)(row + r_) * ldc + col] = acc[mi][ni][r_];
        }
    }
}

// ---------------- K3b: split-K reduction + 1/colS row scale
__global__ __launch_bounds__(256) void k_ctxred(const float* __restrict__ ctxp,
                                                const float* __restrict__ colS,
                                                float* __restrict__ ctx) {
    const long long i4 = ((long long)blockIdx.x * 256 + threadIdx.x) * 4;
    float4 s = make_float4(0.f, 0.f, 0.f, 0.f);
    for (int kc = 0; kc < KS2; ++kc) {
        const float4 v = *reinterpret_cast<const float4*>(ctxp + (long long)kc * (Bb * Cc * Cc) + i4);
        s.x += v.x; s.y += v.y; s.z += v.z; s.w += v.w;
    }
    const int b = (int)(i4 >> 16);
    const int d = ((int)(i4 >> 8)) & 255;
    const float inv = 1.0f / colS[b * Cc + d];
    s.x *= inv; s.y *= inv; s.z *= inv; s.w *= inv;
    *reinterpret_cast<float4*>(ctx + i4) = s;
}

// ---------------- K4: rank + combined top-k softmax coefficients. block per (b,d) row.
__global__ __launch_bounds__(256) void k_rank(const float* __restrict__ ctx,
                                              const float* __restrict__ aw,
                                              float* __restrict__ Ac) {
    __shared__ float row[256];
    __shared__ float red[256];
    const int d = blockIdx.x, b = blockIdx.y, e = threadIdx.x;
    const float c = ctx[((long long)(b * Cc + d)) * Cc + e];
    row[e] = c;
    __syncthreads();
    int p = 0;
    for (int j = 0; j < 256; ++j) {
        const float cj = row[j];
        p += (cj > c) || (cj == c && j < e);  // stable top_k rank (0-based)
    }
    red[e] = c; __syncthreads();
    for (int s_ = 128; s_; s_ >>= 1) { if (e < s_) red[e] = fmaxf(red[e], red[e + s_]); __syncthreads(); }
    const float m = red[0];
    const float ex = __expf(c - m);
    const int kks[4] = {128, 170, 192, 204};
    float Zv[4];
#pragma unroll
    for (int i = 0; i < 4; ++i) {
        __syncthreads();
        red[e] = (p < kks[i]) ? ex : 0.0f;
        __syncthreads();
        for (int s_ = 128; s_; s_ >>= 1) { if (e < s_) red[e] += red[e + s_]; __syncthreads(); }
        Zv[i] = red[0];
    }
    float wsum = 0.0f;
#pragma unroll
    for (int i = 0; i < 4; ++i)
        if (p < kks[i]) wsum += aw[i] / Zv[i];
    Ac[((long long)(b * Cc + d)) * Cc + e] = ex * wsum;
}

// ---------------- K5: WA[b,o,e] = sum_d W[o,d] * A[b,d,e] -> bf16. grid (32, 8), block 256.
__global__ __launch_bounds__(256) void k_wa(const float* __restrict__ W,
                                            const float* __restrict__ Ac,
                                            u16* __restrict__ WAb16) {
    __shared__ float As[16][64], Bs[16][64];
    const int b = blockIdx.y;
    const int o0 = (blockIdx.x >> 2) * 64, e0 = (blockIdx.x & 3) * 64;
    const int t = threadIdx.x, tx = t & 15, ty = t >> 4;
    const int a_oo = t >> 2, a_k4 = (t & 3) * 4;
    const int b_kk = t >> 4, b_e4 = (t & 15) * 4;
    float acc[4][4] = {{0.f}};
    for (int kd = 0; kd < 256; kd += 16) {
        const float4 wv = *reinterpret_cast<const float4*>(W + (o0 + a_oo) * Cc + kd + a_k4);
        const float4 av = *reinterpret_cast<const float4*>(Ac + ((long long)(b * Cc + kd + b_kk)) * Cc + e0 + b_e4);
        __syncthreads();
        As[a_k4 + 0][a_oo] = wv.x; As[a_k4 + 1][a_oo] = wv.y;
        As[a_k4 + 2][a_oo] = wv.z; As[a_k4 + 3][a_oo] = wv.w;
        *reinterpret_cast<float4*>(&Bs[b_kk][b_e4]) = av;
        __syncthreads();
#pragma unroll
        for (int kk = 0; kk < 16; ++kk) {
            const float4 a4 = *reinterpret_cast<const float4*>(&As[kk][ty * 4]);
            const float4 b4 = *reinterpret_cast<const float4*>(&Bs[kk][tx * 4]);
            const float aa[4] = {a4.x, a4.y, a4.z, a4.w};
            const float bb[4] = {b4.x, b4.y, b4.z, b4.w};
#pragma unroll
            for (int i = 0; i < 4; ++i)
#pragma unroll
                for (int j = 0; j < 4; ++j) acc[i][j] = fmaf(aa[i], bb[j], acc[i][j]);
        }
    }
#pragma unroll
    for (int i = 0; i < 4; ++i) {
        int2 pk;
        pk.x = (int)((unsigned)f2bf(acc[i][0]) | ((unsigned)f2bf(acc[i][1]) << 16));
        pk.y = (int)((unsigned)f2bf(acc[i][2]) | ((unsigned)f2bf(acc[i][3]) << 16));
        *reinterpret_cast<int2*>(WAb16 + ((long long)(b * Oo + o0 + ty * 4 + i)) * Cc + e0 + tx * 4) = pk;
    }
}

// ---------------- K7 v3: fused reprojection GEMM + bias + LN(512) + transposed store.
// Zero-LDS GEMM: per-lane fragments loaded directly from global (K=256, no barriers).
// Epilogue: per-wave private transpose patch, float4 stores. 2 barriers total.
// grid (144, 1, 8), block 512 (8 waves: 2 wr x 4 wc). Tile: 64 n x 512 o.
__global__ __launch_bounds__(512) void k_rpln(const u16* __restrict__ Qexp,
                                              const u16* __restrict__ WAb16,
                                              const float* __restrict__ rbias,
                                              const float* __restrict__ nw,
                                              const float* __restrict__ nb,
                                              float* __restrict__ out) {
    __shared__ float patch[8][16][36];          // per-wave 16 o x 32 n (pad 36 -> 16B align)
    __shared__ float psum[64][4], psq[64][4];
    __shared__ float muA[64], rsA[64];

    const int t = threadIdx.x;
    const int b = blockIdx.z;
    const int n0 = blockIdx.x * 64;
    const int l = t & 63, w = t >> 6;
    const int wr = w >> 2, wc = w & 3;          // 2 (M) x 4 (N) waves
    const int frow = l & 15, fk = (l >> 4) << 3;
    const int hi = l >> 4;

    f32x4 acc[2][8] = {};

    // wave-local operand bases: A rows n0+wr*32.., B rows wc*128..
    const u16* Aq = Qexp + ((long long)b * Nn + n0 + wr * 32) * Cc;
    const u16* Bw = WAb16 + ((long long)b * Oo + wc * 128) * Cc;

#pragma unroll
    for (int kt = 0; kt < 4; ++kt) {
#pragma unroll
        for (int kf = 0; kf < 2; ++kf) {
            const int kk = kt * 64 + kf * 32 + fk;
            short8 af[2], bf[8];
#pragma unroll
            for (int mi = 0; mi < 2; ++mi)
                af[mi] = __builtin_bit_cast(short8,
                    *reinterpret_cast<const int4*>(Aq + (mi * 16 + frow) * Cc + kk));
#pragma unroll
            for (int ni = 0; ni < 8; ++ni)
                bf[ni] = __builtin_bit_cast(short8,
                    *reinterpret_cast<const int4*>(Bw + (ni * 16 + frow) * Cc + kk));
#pragma unroll
            for (int mi = 0; mi < 2; ++mi)
#pragma unroll
                for (int ni = 0; ni < 8; ++ni)
                    acc[mi][ni] = __builtin_amdgcn_mfma_f32_16x16x32_bf16(af[mi], bf[ni], acc[mi][ni], 0, 0, 0);
        }
    }

    // ---- epilogue: +bias
#pragma unroll
    for (int ni = 0; ni < 8; ++ni) {
        const float bb = rbias[wc * 128 + ni * 16 + frow];
#pragma unroll
        for (int mi = 0; mi < 2; ++mi)
#pragma unroll
            for (int r_ = 0; r_ < 4; ++r_) acc[mi][ni][r_] += bb;
    }
    // per-row LN partials over this wave's 128 cols
#pragma unroll
    for (int mi = 0; mi < 2; ++mi)
#pragma unroll
        for (int r_ = 0; r_ < 4; ++r_) {
            float s = 0.f, q = 0.f;
#pragma unroll
            for (int ni = 0; ni < 8; ++ni) { const float v = acc[mi][ni][r_]; s += v; q += v * v; }
#pragma unroll
            for (int m = 8; m; m >>= 1) { s += __shfl_xor(s, m); q += __shfl_xor(q, m); }
            if (frow == 0) {
                const int row = wr * 32 + mi * 16 + hi * 4 + r_;
                psum[row][wc] = s; psq[row][wc] = q;
            }
        }
    __syncthreads();
    if (t < 64) {
        const float s = psum[t][0] + psum[t][1] + psum[t][2] + psum[t][3];
        const float q = psq[t][0] + psq[t][1] + psq[t][2] + psq[t][3];
        const float m = s * (1.0f / Oo);
        muA[t] = m;
        rsA[t] = rsqrtf(q * (1.0f / Oo) - m * m + LN_EPS);
    }
    __syncthreads();

    // preload this lane's LN gamma/beta for its 8 o values
    float nwv[8], nbv[8];
#pragma unroll
    for (int ni = 0; ni < 8; ++ni) {
        const int o = wc * 128 + ni * 16 + frow;
        nwv[ni] = nw[o]; nbv[ni] = nb[o];
    }

    // per ni: wave-private 16o x 32n patch -> float4 stores (128-B segments).
    // No block barriers: each wave only touches patch[w].
#pragma unroll
    for (int ni = 0; ni < 8; ++ni) {
#pragma unroll
        for (int mi = 0; mi < 2; ++mi)
#pragma unroll
            for (int r_ = 0; r_ < 4; ++r_) {
                const int nl = mi * 16 + hi * 4 + r_;              // 0..31 within wave
                const int row = wr * 32 + nl;                      // n index in 64-tile
                patch[w][frow][nl] = (acc[mi][ni][r_] - muA[row]) * rsA[row] * nwv[ni] + nbv[ni];
            }
        __builtin_amdgcn_s_waitcnt(0);   // lgkmcnt(0): patch writes visible to own wave
#pragma unroll
        for (int p = 0; p < 2; ++p) {
            const int o_loc = p * 8 + (l >> 3);                    // 0..15
            const int colf4 = l & 7;                               // 0..7
            const float4 v = *reinterpret_cast<const float4*>(&patch[w][o_loc][colf4 * 4]);
            const int o_g = wc * 128 + ni * 16 + o_loc;
            *reinterpret_cast<float4*>(&out[((long long)(b * Oo + o_g)) * Nn + n0 + wr * 32 + colf4 * 4]) = v;
        }
    }
}

extern "C" void kernel_launch(void* const* d_in, const int* in_sizes, int n_in,
                              void* d_out, int out_size, void* d_ws, size_t ws_size,
                              hipStream_t stream) {
    (void)in_sizes; (void)n_in; (void)out_size; (void)ws_size;
    const float* x1    = (const float*)d_in[0];
    const float* x2    = (const float*)d_in[1];
    const float* n1w   = (const float*)d_in[2];
    const float* n1b   = (const float*)d_in[3];
    const float* rw    = (const float*)d_in[4];
    const float* rbias = (const float*)d_in[5];
    const float* n2w   = (const float*)d_in[6];
    const float* n2b   = (const float*)d_in[7];
    const float* aw    = (const float*)d_in[8];
    float* out = (float*)d_out;

    // d_out doubles as scratch for KexpT/VT (dead before k_rpln's final overwrite).
    u16* KexpT = (u16*)d_out;
    u16* VT    = KexpT + (size_t)Bb * Nn * Cc;

    float* ws = (float*)d_ws;
    size_t off = 0;
    u16*   Qexp   = (u16*)(ws + off); off += (size_t)Bb * Nn * Cc / 2;
    float* ctxp   = ws + off; off += (size_t)KS2 * Bb * Cc * Cc;
    float* ctx    = ws + off; off += (size_t)Bb * Cc * Cc;
    float* Ac     = ws + off; off += (size_t)Bb * Cc * Cc;
    u16*   WAb16  = (u16*)(ws + off); off += (size_t)Bb * Oo * Cc / 2;
    float* pS     = ws + off; off += (size_t)Bb * 144 * Cc;
    float* colS   = ws + off; off += (size_t)Bb * Cc;
    float* x1mu   = ws + off; off += (size_t)Bb * Nn;
    float* x1rs   = ws + off; off += (size_t)Bb * Nn;
    float* x2mu   = ws + off; off += (size_t)Bb * Nn;
    float* x2rs   = ws + off; off += (size_t)Bb * Nn;

    k_stat<<<dim3(Bb * Nn / 4), 256, 0, stream>>>(x1, x1mu, x1rs);
    k_ln<<<dim3(Bb * Nn / 4), 256, 0, stream>>>(x2, n1w, n1b, Qexp, x2mu, x2rs);
    k_T<<<dim3(144, 4, Bb), 256, 0, stream>>>(x2, x2mu, x2rs, n1w, n1b, KexpT, pS, 1);
    k_T<<<dim3(144, 4, Bb), 256, 0, stream>>>(x1, x1mu, x1rs, n1w, n1b, VT, pS, 0);
    k_colcomb<<<dim3(Bb), 256, 0, stream>>>(pS, colS);
    k_mm_bf16<<<dim3(4, KS2, Bb), 256, 0, stream>>>(
        KexpT, VT, ctxp,
        Nn, Nn, Cc,
        (long long)Cc * Nn, (long long)Cc * Nn, (long long)Cc * Cc,
        Nn / KS2, (long long)Bb * Cc * Cc,
        Cc / 128, (Nn / KS2) / 64);
    k_ctxred<<<dim3(512), 256, 0, stream>>>(ctxp, colS, ctx);
    k_rank<<<dim3(Cc, Bb), 256, 0, stream>>>(ctx, aw, Ac);
    k_wa<<<dim3(32, Bb), 256, 0, stream>>>(rw, Ac, WAb16);
    k_rpln<<<dim3(144, 1, Bb), 512, 0, stream>>>(Qexp, WAb16, rbias, n2w, n2b, out);
}

// Round 7
// 292.060 us; speedup vs baseline: 2.1211x; 1.1043x over previous
//
#include <hip/hip_runtime.h>
#include <math.h>

typedef __attribute__((ext_vector_type(8))) short short8;
typedef __attribute__((ext_vector_type(4))) float f32x4;
typedef unsigned short u16;

constexpr int Bb = 8;
constexpr int Nn = 9216;   // 96*96
constexpr int Cc = 256;    // = D
constexpr int Oo = 512;    // 2C
constexpr float LN_EPS = 1e-5f;
constexpr int KS2 = 16;    // ctx GEMM split-K chunks (9216 = 16*576)

static __device__ __forceinline__ u16 f2bf(float f) {
    unsigned u = __builtin_bit_cast(unsigned, f);
    u += 0x7fffu + ((u >> 16) & 1u);   // RNE
    return (u16)(u >> 16);
}
static __device__ __forceinline__ float bf2f(u16 u) {
    return __builtin_bit_cast(float, (unsigned)u << 16);
}

// ---------------- K_pre: fused per-input pass. Reads src ONCE (64n x 256d per block).
// Computes per-row LN; writes dstT[b][d][n] bf16 (transposed; exp'd if doExp).
// doExp also: Qexp[b][n][d] = row-softmax(LN) bf16, pS[b][chunk][d] = column partial sums.
// grid (144, 1, 8), block 256.
__global__ __launch_bounds__(256, 4) void k_pre(const float* __restrict__ src,
                                                const float* __restrict__ lnw,
                                                const float* __restrict__ lnb,
                                                u16* __restrict__ dstT,
                                                u16* __restrict__ Qexp,
                                                float* __restrict__ pS,
                                                int doExp) {
    __shared__ u16 tile[256][72];    // [d][n], pad 72 (144B rows, 16B aligned)
    __shared__ float wsh[256], bsh[256];
    const int b = blockIdx.z, nc = blockIdx.x;
    const int n0 = nc * 64;
    const int t = threadIdx.x;
    wsh[t] = lnw[t]; bsh[t] = lnb[t];
    __syncthreads();

    const int r = t >> 2;            // local n row 0..63
    const int g = t & 3;             // col group: cols g*64 .. g*64+63
    const long long row = (long long)b * Nn + n0 + r;
    const float* rowp = src + row * Cc + g * 64;

    float4 v[16];
#pragma unroll
    for (int i = 0; i < 16; ++i) v[i] = *reinterpret_cast<const float4*>(rowp + i * 4);

    float s = 0.f, q = 0.f;
#pragma unroll
    for (int i = 0; i < 16; ++i) {
        s += v[i].x + v[i].y + v[i].z + v[i].w;
        q += v[i].x * v[i].x + v[i].y * v[i].y + v[i].z * v[i].z + v[i].w * v[i].w;
    }
    s += __shfl_xor(s, 1); s += __shfl_xor(s, 2);
    q += __shfl_xor(q, 1); q += __shfl_xor(q, 2);
    const float mu = s * (1.0f / Cc);
    const float rstd = rsqrtf(q * (1.0f / Cc) - mu * mu + LN_EPS);

    float se = 0.f;
#pragma unroll
    for (int i = 0; i < 16; ++i) {
        const float4 w4 = *reinterpret_cast<const float4*>(&wsh[g * 64 + i * 4]);
        const float4 b4 = *reinterpret_cast<const float4*>(&bsh[g * 64 + i * 4]);
        v[i].x = (v[i].x - mu) * rstd * w4.x + b4.x;
        v[i].y = (v[i].y - mu) * rstd * w4.y + b4.y;
        v[i].z = (v[i].z - mu) * rstd * w4.z + b4.z;
        v[i].w = (v[i].w - mu) * rstd * w4.w + b4.w;
        if (doExp) {
            v[i].x = __expf(v[i].x); v[i].y = __expf(v[i].y);
            v[i].z = __expf(v[i].z); v[i].w = __expf(v[i].w);
            se += v[i].x + v[i].y + v[i].z + v[i].w;
        }
        const int d = g * 64 + i * 4;
        tile[d + 0][r] = f2bf(v[i].x);
        tile[d + 1][r] = f2bf(v[i].y);
        tile[d + 2][r] = f2bf(v[i].z);
        tile[d + 3][r] = f2bf(v[i].w);
    }

    if (doExp) {
        se += __shfl_xor(se, 1); se += __shfl_xor(se, 2);
        const float inv = 1.0f / se;
#pragma unroll
        for (int i2 = 0; i2 < 2; ++i2) {
            int4 pk;
            const float4 a = v[i2 * 8 + 0], c = v[i2 * 8 + 1];
            const float4 e = v[i2 * 8 + 2], f = v[i2 * 8 + 3];
            // pack 16 bf16 per int4 pair? int4 = 8 u16; do 4 int4 per 8 float4s:
            pk.x = (int)((unsigned)f2bf(a.x * inv) | ((unsigned)f2bf(a.y * inv) << 16));
            pk.y = (int)((unsigned)f2bf(a.z * inv) | ((unsigned)f2bf(a.w * inv) << 16));
            pk.z = (int)((unsigned)f2bf(c.x * inv) | ((unsigned)f2bf(c.y * inv) << 16));
            pk.w = (int)((unsigned)f2bf(c.z * inv) | ((unsigned)f2bf(c.w * inv) << 16));
            *reinterpret_cast<int4*>(Qexp + row * Cc + g * 64 + i2 * 32) = pk;
            int4 pk2;
            pk2.x = (int)((unsigned)f2bf(e.x * inv) | ((unsigned)f2bf(e.y * inv) << 16));
            pk2.y = (int)((unsigned)f2bf(e.z * inv) | ((unsigned)f2bf(e.w * inv) << 16));
            pk2.z = (int)((unsigned)f2bf(f.x * inv) | ((unsigned)f2bf(f.y * inv) << 16));
            pk2.w = (int)((unsigned)f2bf(f.z * inv) | ((unsigned)f2bf(f.w * inv) << 16));
            *reinterpret_cast<int4*>(Qexp + row * Cc + g * 64 + i2 * 32 + 8) = pk2;
            int4 pk3;
            const float4 a2 = v[i2 * 8 + 4], c2 = v[i2 * 8 + 5];
            const float4 e2 = v[i2 * 8 + 6], f2 = v[i2 * 8 + 7];
            pk3.x = (int)((unsigned)f2bf(a2.x * inv) | ((unsigned)f2bf(a2.y * inv) << 16));
            pk3.y = (int)((unsigned)f2bf(a2.z * inv) | ((unsigned)f2bf(a2.w * inv) << 16));
            pk3.z = (int)((unsigned)f2bf(c2.x * inv) | ((unsigned)f2bf(c2.y * inv) << 16));
            pk3.w = (int)((unsigned)f2bf(c2.z * inv) | ((unsigned)f2bf(c2.w * inv) << 16));
            *reinterpret_cast<int4*>(Qexp + row * Cc + g * 64 + i2 * 32 + 16) = pk3;
            int4 pk4;
            pk4.x = (int)((unsigned)f2bf(e2.x * inv) | ((unsigned)f2bf(e2.y * inv) << 16));
            pk4.y = (int)((unsigned)f2bf(e2.z * inv) | ((unsigned)f2bf(e2.w * inv) << 16));
            pk4.z = (int)((unsigned)f2bf(f2.x * inv) | ((unsigned)f2bf(f2.y * inv) << 16));
            pk4.w = (int)((unsigned)f2bf(f2.z * inv) | ((unsigned)f2bf(f2.w * inv) << 16));
            *reinterpret_cast<int4*>(Qexp + row * Cc + g * 64 + i2 * 32 + 24) = pk4;
        }
    }
    __syncthreads();

    // transposed output + column partial sums
#pragma unroll
    for (int p = 0; p < 8; ++p) {
        const int d = p * 32 + (t >> 3);
        const int c = (t & 7) * 8;
        const int4 u = *reinterpret_cast<const int4*>(&tile[d][c]);
        *reinterpret_cast<int4*>(dstT + ((long long)(b * Cc + d)) * Nn + n0 + c) = u;
        if (doExp) {
            const unsigned uu[4] = {(unsigned)u.x, (unsigned)u.y, (unsigned)u.z, (unsigned)u.w};
            float ss = 0.f;
#pragma unroll
            for (int j = 0; j < 4; ++j) {
                ss += bf2f((u16)(uu[j] & 0xffff));
                ss += bf2f((u16)(uu[j] >> 16));
            }
            ss += __shfl_xor(ss, 1);
            ss += __shfl_xor(ss, 2);
            ss += __shfl_xor(ss, 4);
            if ((t & 7) == 0) pS[((long long)b * 144 + nc) * Cc + d] = ss;
        }
    }
}

// ---------------- K2b: colS[b][d] = sum over 144 chunks
__global__ __launch_bounds__(256) void k_colcomb(const float* __restrict__ pS,
                                                 float* __restrict__ colS) {
    const int d = threadIdx.x, b = blockIdx.x;
    float s = 0.f;
    for (int c = 0; c < 144; ++c) s += pS[((long long)b * 144 + c) * Cc + d];
    colS[b * Cc + d] = s;
}

// ---------------- K6: bf16 MFMA GEMM (ctx).  C[m][n] = sum_k A[m][k] * Bt[n][k]
__global__ __launch_bounds__(256) void k_mm_bf16(const u16* __restrict__ A,
                                                 const u16* __restrict__ Bt,
                                                 float* __restrict__ C,
                                                 int lda, int ldb, int ldc,
                                                 long long sAb, long long sBb, long long sCb,
                                                 int kChunk, long long sCk,
                                                 int tilesN, int kIters) {
    __shared__ alignas(16) u16 Asm[128 * 64];
    __shared__ alignas(16) u16 Bsm[128 * 64];
    const int t = threadIdx.x;
    const int b = blockIdx.z, kc = blockIdx.y;
    const int tm = blockIdx.x / tilesN, tn = blockIdx.x % tilesN;
    const int m0 = tm * 128, n0 = tn * 128;
    const u16* Ag = A + b * sAb + (long long)kc * kChunk;
    const u16* Bg = Bt + b * sBb + (long long)kc * kChunk;
    float* Cg = C + b * sCb + (long long)kc * sCk;

    const int l = t & 63, w = t >> 6;
    const int wr = w >> 1, wc = w & 1;
    const int frow = l & 15, fk = (l >> 4) << 3;

    f32x4 acc[4][4] = {};

    for (int kt = 0; kt < kIters; ++kt) {
        const int k0 = kt * 64;
        int4 av[4], bv[4];
#pragma unroll
        for (int i = 0; i < 4; ++i) {
            const int s = t + 256 * i;
            const int r = s >> 3, c16 = s & 7;
            av[i] = *reinterpret_cast<const int4*>(Ag + (long long)(m0 + r) * lda + k0 + c16 * 8);
            bv[i] = *reinterpret_cast<const int4*>(Bg + (long long)(n0 + r) * ldb + k0 + c16 * 8);
        }
        __syncthreads();
#pragma unroll
        for (int i = 0; i < 4; ++i) {
            const int s = t + 256 * i;
            const int r = s >> 3, c16 = s & 7;
            const int idx = r * 64 + ((c16 * 8) ^ ((r & 7) << 3));
            *reinterpret_cast<int4*>(&Asm[idx]) = av[i];
            *reinterpret_cast<int4*>(&Bsm[idx]) = bv[i];
        }
        __syncthreads();
#pragma unroll
        for (int kf = 0; kf < 2; ++kf) {
            short8 af[4], bf[4];
            const int kk = kf * 32 + fk;
#pragma unroll
            for (int mi = 0; mi < 4; ++mi) {
                const int row = wr * 64 + mi * 16 + frow;
                af[mi] = *reinterpret_cast<const short8*>(&Asm[row * 64 + (kk ^ ((row & 7) << 3))]);
            }
#pragma unroll
            for (int ni = 0; ni < 4; ++ni) {
                const int row = wc * 64 + ni * 16 + frow;
                bf[ni] = *reinterpret_cast<const short8*>(&Bsm[row * 64 + (kk ^ ((row & 7) << 3))]);
            }
#pragma unroll
            for (int mi = 0; mi < 4; ++mi)
#pragma unroll
                for (int ni = 0; ni < 4; ++ni)
                    acc[mi][ni] = __builtin_amdgcn_mfma_f32_16x16x32_bf16(af[mi], bf[ni], acc[mi][ni], 0, 0, 0);
        }
    }

    const int crow0 = (l >> 4) * 4, ccol = l & 15;
#pragma unroll
    for (int mi = 0; mi < 4; ++mi) {
#pragma unroll
        for (int ni = 0; ni < 4; ++ni) {
            const int row = m0 + wr * 64 + mi * 16 + crow0;
            const int col = n0 + wc * 64 + ni * 16 + ccol;
#pragma unroll
            for (int r_ = 0; r_ < 4; ++r_)
                Cg[(long long)(row + r_) * ldc + col] = acc[mi][ni][r_];
        }
    }
}

// ---------------- K3b: split-K reduction + 1/colS row scale
__global__ __launch_bounds__(256) void k_ctxred(const float* __restrict__ ctxp,
                                                const float* __restrict__ colS,
                                                float* __restrict__ ctx) {
    const long long i4 = ((long long)blockIdx.x * 256 + threadIdx.x) * 4;
    float4 s = make_float4(0.f, 0.f, 0.f, 0.f);
    for (int kc = 0; kc < KS2; ++kc) {
        const float4 v = *reinterpret_cast<const float4*>(ctxp + (long long)kc * (Bb * Cc * Cc) + i4);
        s.x += v.x; s.y += v.y; s.z += v.z; s.w += v.w;
    }
    const int b = (int)(i4 >> 16);
    const int d = ((int)(i4 >> 8)) & 255;
    const float inv = 1.0f / colS[b * Cc + d];
    s.x *= inv; s.y *= inv; s.z *= inv; s.w *= inv;
    *reinterpret_cast<float4*>(ctx + i4) = s;
}

// ---------------- K4: rank + combined top-k softmax coefficients. block per (b,d) row.
__global__ __launch_bounds__(256) void k_rank(const float* __restrict__ ctx,
                                              const float* __restrict__ aw,
                                              float* __restrict__ Ac) {
    __shared__ float row[256];
    __shared__ float red[256];
    const int d = blockIdx.x, b = blockIdx.y, e = threadIdx.x;
    const float c = ctx[((long long)(b * Cc + d)) * Cc + e];
    row[e] = c;
    __syncthreads();
    int p = 0;
    for (int j = 0; j < 256; ++j) {
        const float cj = row[j];
        p += (cj > c) || (cj == c && j < e);  // stable top_k rank (0-based)
    }
    red[e] = c; __syncthreads();
    for (int s_ = 128; s_; s_ >>= 1) { if (e < s_) red[e] = fmaxf(red[e], red[e + s_]); __syncthreads(); }
    const float m = red[0];
    const float ex = __expf(c - m);
    const int kks[4] = {128, 170, 192, 204};
    float Zv[4];
#pragma unroll
    for (int i = 0; i < 4; ++i) {
        __syncthreads();
        red[e] = (p < kks[i]) ? ex : 0.0f;
        __syncthreads();
        for (int s_ = 128; s_; s_ >>= 1) { if (e < s_) red[e] += red[e + s_]; __syncthreads(); }
        Zv[i] = red[0];
    }
    float wsum = 0.0f;
#pragma unroll
    for (int i = 0; i < 4; ++i)
        if (p < kks[i]) wsum += aw[i] / Zv[i];
    Ac[((long long)(b * Cc + d)) * Cc + e] = ex * wsum;
}

// ---------------- K5: WA[b,o,e] = sum_d W[o,d] * A[b,d,e] -> bf16. grid (32, 8), block 256.
__global__ __launch_bounds__(256) void k_wa(const float* __restrict__ W,
                                            const float* __restrict__ Ac,
                                            u16* __restrict__ WAb16) {
    __shared__ float As[16][64], Bs[16][64];
    const int b = blockIdx.y;
    const int o0 = (blockIdx.x >> 2) * 64, e0 = (blockIdx.x & 3) * 64;
    const int t = threadIdx.x, tx = t & 15, ty = t >> 4;
    const int a_oo = t >> 2, a_k4 = (t & 3) * 4;
    const int b_kk = t >> 4, b_e4 = (t & 15) * 4;
    float acc[4][4] = {{0.f}};
    for (int kd = 0; kd < 256; kd += 16) {
        const float4 wv = *reinterpret_cast<const float4*>(W + (o0 + a_oo) * Cc + kd + a_k4);
        const float4 av = *reinterpret_cast<const float4*>(Ac + ((long long)(b * Cc + kd + b_kk)) * Cc + e0 + b_e4);
        __syncthreads();
        As[a_k4 + 0][a_oo] = wv.x; As[a_k4 + 1][a_oo] = wv.y;
        As[a_k4 + 2][a_oo] = wv.z; As[a_k4 + 3][a_oo] = wv.w;
        *reinterpret_cast<float4*>(&Bs[b_kk][b_e4]) = av;
        __syncthreads();
#pragma unroll
        for (int kk = 0; kk < 16; ++kk) {
            const float4 a4 = *reinterpret_cast<const float4*>(&As[kk][ty * 4]);
            const float4 b4 = *reinterpret_cast<const float4*>(&Bs[kk][tx * 4]);
            const float aa[4] = {a4.x, a4.y, a4.z, a4.w};
            const float bb[4] = {b4.x, b4.y, b4.z, b4.w};
#pragma unroll
            for (int i = 0; i < 4; ++i)
#pragma unroll
                for (int j = 0; j < 4; ++j) acc[i][j] = fmaf(aa[i], bb[j], acc[i][j]);
        }
    }
#pragma unroll
    for (int i = 0; i < 4; ++i) {
        int2 pk;
        pk.x = (int)((unsigned)f2bf(acc[i][0]) | ((unsigned)f2bf(acc[i][1]) << 16));
        pk.y = (int)((unsigned)f2bf(acc[i][2]) | ((unsigned)f2bf(acc[i][3]) << 16));
        *reinterpret_cast<int2*>(WAb16 + ((long long)(b * Oo + o0 + ty * 4 + i)) * Cc + e0 + tx * 4) = pk;
    }
}

// ---------------- K7 v4: fused reprojection GEMM + bias + LN(512) + transposed store.
// Zero-LDS GEMM with explicit 1-step software pipeline (prefetch next K-step).
// grid (288, 1, 8), block 256 (4 waves, each 32n x 128o). Tile: 32 n x 512 o.
__global__ __launch_bounds__(256, 3) void k_rpln(const u16* __restrict__ Qexp,
                                                 const u16* __restrict__ WAb16,
                                                 const float* __restrict__ rbias,
                                                 const float* __restrict__ nw,
                                                 const float* __restrict__ nb,
                                                 float* __restrict__ out) {
    __shared__ float patch[4][16][36];          // per-wave 16 o x 32 n
    __shared__ float psum[32][4], psq[32][4];
    __shared__ float muA[32], rsA[32];

    const int t = threadIdx.x;
    const int b = blockIdx.z;
    const int n0 = blockIdx.x * 32;
    const int l = t & 63, w = t >> 6;           // 4 waves; wave w owns o = w*128..
    const int frow = l & 15, fk = (l >> 4) << 3;
    const int hi = l >> 4;

    f32x4 acc[2][8] = {};

    const u16* Aq = Qexp + ((long long)b * Nn + n0) * Cc;
    const u16* Bw = WAb16 + ((long long)b * Oo + w * 128) * Cc;

    int4 aC[2], bC[8];
#pragma unroll
    for (int mi = 0; mi < 2; ++mi)
        aC[mi] = *reinterpret_cast<const int4*>(Aq + (mi * 16 + frow) * Cc + fk);
#pragma unroll
    for (int ni = 0; ni < 8; ++ni)
        bC[ni] = *reinterpret_cast<const int4*>(Bw + (ni * 16 + frow) * Cc + fk);

#pragma unroll
    for (int s = 0; s < 8; ++s) {
        int4 aN[2], bN[8];
        if (s < 7) {
            const int kk = (s + 1) * 32 + fk;
#pragma unroll
            for (int mi = 0; mi < 2; ++mi)
                aN[mi] = *reinterpret_cast<const int4*>(Aq + (mi * 16 + frow) * Cc + kk);
#pragma unroll
            for (int ni = 0; ni < 8; ++ni)
                bN[ni] = *reinterpret_cast<const int4*>(Bw + (ni * 16 + frow) * Cc + kk);
        }
#pragma unroll
        for (int mi = 0; mi < 2; ++mi)
#pragma unroll
            for (int ni = 0; ni < 8; ++ni)
                acc[mi][ni] = __builtin_amdgcn_mfma_f32_16x16x32_bf16(
                    __builtin_bit_cast(short8, aC[mi]), __builtin_bit_cast(short8, bC[ni]),
                    acc[mi][ni], 0, 0, 0);
        if (s < 7) {
#pragma unroll
            for (int mi = 0; mi < 2; ++mi) aC[mi] = aN[mi];
#pragma unroll
            for (int ni = 0; ni < 8; ++ni) bC[ni] = bN[ni];
        }
    }

    // ---- epilogue: +bias
#pragma unroll
    for (int ni = 0; ni < 8; ++ni) {
        const float bb = rbias[w * 128 + ni * 16 + frow];
#pragma unroll
        for (int mi = 0; mi < 2; ++mi)
#pragma unroll
            for (int r_ = 0; r_ < 4; ++r_) acc[mi][ni][r_] += bb;
    }
    // per-row LN partials over this wave's 128 cols
#pragma unroll
    for (int mi = 0; mi < 2; ++mi)
#pragma unroll
        for (int r_ = 0; r_ < 4; ++r_) {
            float s = 0.f, q = 0.f;
#pragma unroll
            for (int ni = 0; ni < 8; ++ni) { const float v = acc[mi][ni][r_]; s += v; q += v * v; }
#pragma unroll
            for (int m = 8; m; m >>= 1) { s += __shfl_xor(s, m); q += __shfl_xor(q, m); }
            if (frow == 0) {
                const int row = mi * 16 + hi * 4 + r_;
                psum[row][w] = s; psq[row][w] = q;
            }
        }
    __syncthreads();
    if (t < 32) {
        const float s = psum[t][0] + psum[t][1] + psum[t][2] + psum[t][3];
        const float q = psq[t][0] + psq[t][1] + psq[t][2] + psq[t][3];
        const float m = s * (1.0f / Oo);
        muA[t] = m;
        rsA[t] = rsqrtf(q * (1.0f / Oo) - m * m + LN_EPS);
    }
    __syncthreads();

    float nwv[8], nbv[8];
#pragma unroll
    for (int ni = 0; ni < 8; ++ni) {
        const int o = w * 128 + ni * 16 + frow;
        nwv[ni] = nw[o]; nbv[ni] = nb[o];
    }

    // per ni: wave-private 16o x 32n patch -> float4 stores (128-B segments).
#pragma unroll
    for (int ni = 0; ni < 8; ++ni) {
#pragma unroll
        for (int mi = 0; mi < 2; ++mi)
#pragma unroll
            for (int r_ = 0; r_ < 4; ++r_) {
                const int nl = mi * 16 + hi * 4 + r_;              // 0..31
                patch[w][frow][nl] = (acc[mi][ni][r_] - muA[nl]) * rsA[nl] * nwv[ni] + nbv[ni];
            }
        asm volatile("s_waitcnt lgkmcnt(0)" ::: "memory");
        __builtin_amdgcn_sched_barrier(0);
#pragma unroll
        for (int p = 0; p < 2; ++p) {
            const int o_loc = p * 8 + (l >> 3);                    // 0..15
            const int colf4 = l & 7;                               // 0..7
            const float4 v = *reinterpret_cast<const float4*>(&patch[w][o_loc][colf4 * 4]);
            const int o_g = w * 128 + ni * 16 + o_loc;
            *reinterpret_cast<float4*>(&out[((long long)(b * Oo + o_g)) * Nn + n0 + colf4 * 4]) = v;
        }
        asm volatile("s_waitcnt lgkmcnt(0)" ::: "memory");
        __builtin_amdgcn_sched_barrier(0);
    }
}

extern "C" void kernel_launch(void* const* d_in, const int* in_sizes, int n_in,
                              void* d_out, int out_size, void* d_ws, size_t ws_size,
                              hipStream_t stream) {
    (void)in_sizes; (void)n_in; (void)out_size; (void)ws_size;
    const float* x1    = (const float*)d_in[0];
    const float* x2    = (const float*)d_in[1];
    const float* n1w   = (const float*)d_in[2];
    const float* n1b   = (const float*)d_in[3];
    const float* rw    = (const float*)d_in[4];
    const float* rbias = (const float*)d_in[5];
    const float* n2w   = (const float*)d_in[6];
    const float* n2b   = (const float*)d_in[7];
    const float* aw    = (const float*)d_in[8];
    float* out = (float*)d_out;

    // d_out doubles as scratch for KexpT/VT (dead before k_rpln's final overwrite).
    u16* KexpT = (u16*)d_out;
    u16* VT    = KexpT + (size_t)Bb * Nn * Cc;

    float* ws = (float*)d_ws;
    size_t off = 0;
    u16*   Qexp   = (u16*)(ws + off); off += (size_t)Bb * Nn * Cc / 2;  //  9.4M f32
    float* ctxp   = ws + off; off += (size_t)KS2 * Bb * Cc * Cc;        //  8.4M f32
    float* ctx    = ws + off; off += (size_t)Bb * Cc * Cc;
    float* Ac     = ws + off; off += (size_t)Bb * Cc * Cc;
    u16*   WAb16  = (u16*)(ws + off); off += (size_t)Bb * Oo * Cc / 2;
    float* pS     = ws + off; off += (size_t)Bb * 144 * Cc;
    float* colS   = ws + off; off += (size_t)Bb * Cc;

    // x2 pass: KexpT (exp'd transpose), Qexp (row softmax), pS (col partials)
    k_pre<<<dim3(144, 1, Bb), 256, 0, stream>>>(x2, n1w, n1b, KexpT, Qexp, pS, 1);
    // x1 pass: VT (plain LN transpose)
    k_pre<<<dim3(144, 1, Bb), 256, 0, stream>>>(x1, n1w, n1b, VT, Qexp, pS, 0);
    k_colcomb<<<dim3(Bb), 256, 0, stream>>>(pS, colS);
    k_mm_bf16<<<dim3(4, KS2, Bb), 256, 0, stream>>>(
        KexpT, VT, ctxp,
        Nn, Nn, Cc,
        (long long)Cc * Nn, (long long)Cc * Nn, (long long)Cc * Cc,
        Nn / KS2, (long long)Bb * Cc * Cc,
        Cc / 128, (Nn / KS2) / 64);
    k_ctxred<<<dim3(512), 256, 0, stream>>>(ctxp, colS, ctx);
    k_rank<<<dim3(Cc, Bb), 256, 0, stream>>>(ctx, aw, Ac);
    k_wa<<<dim3(32, Bb), 256, 0, stream>>>(rw, Ac, WAb16);
    k_rpln<<<dim3(288, 1, Bb), 256, 0, stream>>>(Qexp, WAb16, rbias, n2w, n2b, out);
}

// Round 8
// 272.498 us; speedup vs baseline: 2.2734x; 1.0718x over previous
//
#include <hip/hip_runtime.h>
#include <math.h>

typedef __attribute__((ext_vector_type(8))) short short8;
typedef __attribute__((ext_vector_type(4))) float f32x4;
typedef unsigned short u16;

constexpr int Bb = 8;
constexpr int Nn = 9216;   // 96*96
constexpr int Cc = 256;    // = D
constexpr int Oo = 512;    // 2C
constexpr float LN_EPS = 1e-5f;
constexpr int KS2 = 16;    // ctx GEMM split-K chunks (9216 = 16*576)

static __device__ __forceinline__ u16 f2bf(float f) {
    unsigned u = __builtin_bit_cast(unsigned, f);
    u += 0x7fffu + ((u >> 16) & 1u);   // RNE
    return (u16)(u >> 16);
}
static __device__ __forceinline__ float bf2f(u16 u) {
    return __builtin_bit_cast(float, (unsigned)u << 16);
}

// ---------------- K_pre v2: fused per-input pass (512 threads, 64n x 256d per block).
// Per-row LN; dstT[b][d][n] bf16 (exp'd if doExp); doExp also Qexp row-softmax + pS col partials.
// Thread (r = t>>3, g = t&7) owns row n0+r, cols d = g*4 + i*32 (i=0..7).
__global__ __launch_bounds__(512, 2) void k_pre(const float* __restrict__ src,
                                                const float* __restrict__ lnw,
                                                const float* __restrict__ lnb,
                                                u16* __restrict__ dstT,
                                                u16* __restrict__ Qexp,
                                                float* __restrict__ pS,
                                                int doExp) {
    __shared__ u16 tile[256][72];    // [d][n], pad 72 u16 (144 B rows)
    __shared__ float wsh[256], bsh[256];
    const int b = blockIdx.z, nc = blockIdx.x;
    const int n0 = nc * 64;
    const int t = threadIdx.x;
    if (t < 256) { wsh[t] = lnw[t]; bsh[t] = lnb[t]; }
    __syncthreads();

    const int r = t >> 3;            // 0..63
    const int g = t & 7;             // 0..7
    const long long row = (long long)b * Nn + n0 + r;
    const float* rowp = src + row * Cc;

    float4 v[8];
#pragma unroll
    for (int i = 0; i < 8; ++i)
        v[i] = *reinterpret_cast<const float4*>(rowp + g * 4 + i * 32);

    float s = 0.f, q = 0.f;
#pragma unroll
    for (int i = 0; i < 8; ++i) {
        s += v[i].x + v[i].y + v[i].z + v[i].w;
        q += v[i].x * v[i].x + v[i].y * v[i].y + v[i].z * v[i].z + v[i].w * v[i].w;
    }
    s += __shfl_xor(s, 1); s += __shfl_xor(s, 2); s += __shfl_xor(s, 4);
    q += __shfl_xor(q, 1); q += __shfl_xor(q, 2); q += __shfl_xor(q, 4);
    const float mu = s * (1.0f / Cc);
    const float rstd = rsqrtf(q * (1.0f / Cc) - mu * mu + LN_EPS);

    float se = 0.f;
#pragma unroll
    for (int i = 0; i < 8; ++i) {
        const int d = g * 4 + i * 32;
        const float4 w4 = *reinterpret_cast<const float4*>(&wsh[d]);
        const float4 b4 = *reinterpret_cast<const float4*>(&bsh[d]);
        v[i].x = (v[i].x - mu) * rstd * w4.x + b4.x;
        v[i].y = (v[i].y - mu) * rstd * w4.y + b4.y;
        v[i].z = (v[i].z - mu) * rstd * w4.z + b4.z;
        v[i].w = (v[i].w - mu) * rstd * w4.w + b4.w;
        if (doExp) {
            v[i].x = __expf(v[i].x); v[i].y = __expf(v[i].y);
            v[i].z = __expf(v[i].z); v[i].w = __expf(v[i].w);
            se += v[i].x + v[i].y + v[i].z + v[i].w;
        }
        tile[d + 0][r] = f2bf(v[i].x);
        tile[d + 1][r] = f2bf(v[i].y);
        tile[d + 2][r] = f2bf(v[i].z);
        tile[d + 3][r] = f2bf(v[i].w);
    }

    if (doExp) {
        se += __shfl_xor(se, 1); se += __shfl_xor(se, 2); se += __shfl_xor(se, 4);
        const float inv = 1.0f / se;
#pragma unroll
        for (int i = 0; i < 8; ++i) {
            const int d = g * 4 + i * 32;
            int2 pk;
            pk.x = (int)((unsigned)f2bf(v[i].x * inv) | ((unsigned)f2bf(v[i].y * inv) << 16));
            pk.y = (int)((unsigned)f2bf(v[i].z * inv) | ((unsigned)f2bf(v[i].w * inv) << 16));
            *reinterpret_cast<int2*>(Qexp + row * Cc + d) = pk;
        }
    }
    __syncthreads();

    // transposed global write: thread (d = p*64 + t>>3, c = (t&7)*8), p = 0..3
#pragma unroll
    for (int p = 0; p < 4; ++p) {
        const int d = p * 64 + (t >> 3);
        const int c = (t & 7) * 8;
        const int4 u = *reinterpret_cast<const int4*>(&tile[d][c]);
        *reinterpret_cast<int4*>(dstT + ((long long)(b * Cc + d)) * Nn + n0 + c) = u;
        if (doExp) {
            const unsigned uu[4] = {(unsigned)u.x, (unsigned)u.y, (unsigned)u.z, (unsigned)u.w};
            float ss = 0.f;
#pragma unroll
            for (int j = 0; j < 4; ++j) {
                ss += bf2f((u16)(uu[j] & 0xffff));
                ss += bf2f((u16)(uu[j] >> 16));
            }
            ss += __shfl_xor(ss, 1);
            ss += __shfl_xor(ss, 2);
            ss += __shfl_xor(ss, 4);
            if ((t & 7) == 0) pS[((long long)b * 144 + nc) * Cc + d] = ss;
        }
    }
}

// ---------------- K2b: colS[b][d] = sum over 144 chunks
__global__ __launch_bounds__(256) void k_colcomb(const float* __restrict__ pS,
                                                 float* __restrict__ colS) {
    const int d = threadIdx.x, b = blockIdx.x;
    float s = 0.f;
    for (int c = 0; c < 144; ++c) s += pS[((long long)b * 144 + c) * Cc + d];
    colS[b * Cc + d] = s;
}

// ---------------- K6: bf16 MFMA GEMM (ctx).  C[m][n] = sum_k A[m][k] * Bt[n][k]
__global__ __launch_bounds__(256) void k_mm_bf16(const u16* __restrict__ A,
                                                 const u16* __restrict__ Bt,
                                                 float* __restrict__ C,
                                                 int lda, int ldb, int ldc,
                                                 long long sAb, long long sBb, long long sCb,
                                                 int kChunk, long long sCk,
                                                 int tilesN, int kIters) {
    __shared__ alignas(16) u16 Asm[128 * 64];
    __shared__ alignas(16) u16 Bsm[128 * 64];
    const int t = threadIdx.x;
    const int b = blockIdx.z, kc = blockIdx.y;
    const int tm = blockIdx.x / tilesN, tn = blockIdx.x % tilesN;
    const int m0 = tm * 128, n0 = tn * 128;
    const u16* Ag = A + b * sAb + (long long)kc * kChunk;
    const u16* Bg = Bt + b * sBb + (long long)kc * kChunk;
    float* Cg = C + b * sCb + (long long)kc * sCk;

    const int l = t & 63, w = t >> 6;
    const int wr = w >> 1, wc = w & 1;
    const int frow = l & 15, fk = (l >> 4) << 3;

    f32x4 acc[4][4] = {};

    for (int kt = 0; kt < kIters; ++kt) {
        const int k0 = kt * 64;
        int4 av[4], bv[4];
#pragma unroll
        for (int i = 0; i < 4; ++i) {
            const int s = t + 256 * i;
            const int r = s >> 3, c16 = s & 7;
            av[i] = *reinterpret_cast<const int4*>(Ag + (long long)(m0 + r) * lda + k0 + c16 * 8);
            bv[i] = *reinterpret_cast<const int4*>(Bg + (long long)(n0 + r) * ldb + k0 + c16 * 8);
        }
        __syncthreads();
#pragma unroll
        for (int i = 0; i < 4; ++i) {
            const int s = t + 256 * i;
            const int r = s >> 3, c16 = s & 7;
            const int idx = r * 64 + ((c16 * 8) ^ ((r & 7) << 3));
            *reinterpret_cast<int4*>(&Asm[idx]) = av[i];
            *reinterpret_cast<int4*>(&Bsm[idx]) = bv[i];
        }
        __syncthreads();
#pragma unroll
        for (int kf = 0; kf < 2; ++kf) {
            short8 af[4], bf[4];
            const int kk = kf * 32 + fk;
#pragma unroll
            for (int mi = 0; mi < 4; ++mi) {
                const int row = wr * 64 + mi * 16 + frow;
                af[mi] = *reinterpret_cast<const short8*>(&Asm[row * 64 + (kk ^ ((row & 7) << 3))]);
            }
#pragma unroll
            for (int ni = 0; ni < 4; ++ni) {
                const int row = wc * 64 + ni * 16 + frow;
                bf[ni] = *reinterpret_cast<const short8*>(&Bsm[row * 64 + (kk ^ ((row & 7) << 3))]);
            }
#pragma unroll
            for (int mi = 0; mi < 4; ++mi)
#pragma unroll
                for (int ni = 0; ni < 4; ++ni)
                    acc[mi][ni] = __builtin_amdgcn_mfma_f32_16x16x32_bf16(af[mi], bf[ni], acc[mi][ni], 0, 0, 0);
        }
    }

    const int crow0 = (l >> 4) * 4, ccol = l & 15;
#pragma unroll
    for (int mi = 0; mi < 4; ++mi) {
#pragma unroll
        for (int ni = 0; ni < 4; ++ni) {
            const int row = m0 + wr * 64 + mi * 16 + crow0;
            const int col = n0 + wc * 64 + ni * 16 + ccol;
#pragma unroll
            for (int r_ = 0; r_ < 4; ++r_)
                Cg[(long long)(row + r_) * ldc + col] = acc[mi][ni][r_];
        }
    }
}

// ---------------- K3b: split-K reduction + 1/colS row scale
__global__ __launch_bounds__(256) void k_ctxred(const float* __restrict__ ctxp,
                                                const float* __restrict__ colS,
                                                float* __restrict__ ctx) {
    const long long i4 = ((long long)blockIdx.x * 256 + threadIdx.x) * 4;
    float4 s = make_float4(0.f, 0.f, 0.f, 0.f);
    for (int kc = 0; kc < KS2; ++kc) {
        const float4 v = *reinterpret_cast<const float4*>(ctxp + (long long)kc * (Bb * Cc * Cc) + i4);
        s.x += v.x; s.y += v.y; s.z += v.z; s.w += v.w;
    }
    const int b = (int)(i4 >> 16);
    const int d = ((int)(i4 >> 8)) & 255;
    const float inv = 1.0f / colS[b * Cc + d];
    s.x *= inv; s.y *= inv; s.z *= inv; s.w *= inv;
    *reinterpret_cast<float4*>(ctx + i4) = s;
}

// ---------------- K4: rank + combined top-k softmax coefficients. block per (b,d) row.
__global__ __launch_bounds__(256) void k_rank(const float* __restrict__ ctx,
                                              const float* __restrict__ aw,
                                              float* __restrict__ Ac) {
    __shared__ float row[256];
    __shared__ float red[256];
    const int d = blockIdx.x, b = blockIdx.y, e = threadIdx.x;
    const float c = ctx[((long long)(b * Cc + d)) * Cc + e];
    row[e] = c;
    __syncthreads();
    int p = 0;
    for (int j = 0; j < 256; ++j) {
        const float cj = row[j];
        p += (cj > c) || (cj == c && j < e);  // stable top_k rank (0-based)
    }
    red[e] = c; __syncthreads();
    for (int s_ = 128; s_; s_ >>= 1) { if (e < s_) red[e] = fmaxf(red[e], red[e + s_]); __syncthreads(); }
    const float m = red[0];
    const float ex = __expf(c - m);
    const int kks[4] = {128, 170, 192, 204};
    float Zv[4];
#pragma unroll
    for (int i = 0; i < 4; ++i) {
        __syncthreads();
        red[e] = (p < kks[i]) ? ex : 0.0f;
        __syncthreads();
        for (int s_ = 128; s_; s_ >>= 1) { if (e < s_) red[e] += red[e + s_]; __syncthreads(); }
        Zv[i] = red[0];
    }
    float wsum = 0.0f;
#pragma unroll
    for (int i = 0; i < 4; ++i)
        if (p < kks[i]) wsum += aw[i] / Zv[i];
    Ac[((long long)(b * Cc + d)) * Cc + e] = ex * wsum;
}

// ---------------- K5: WA[b,o,e] = sum_d W[o,d] * A[b,d,e] -> bf16. grid (32, 8), block 256.
__global__ __launch_bounds__(256) void k_wa(const float* __restrict__ W,
                                            const float* __restrict__ Ac,
                                            u16* __restrict__ WAb16) {
    __shared__ float As[16][64], Bs[16][64];
    const int b = blockIdx.y;
    const int o0 = (blockIdx.x >> 2) * 64, e0 = (blockIdx.x & 3) * 64;
    const int t = threadIdx.x, tx = t & 15, ty = t >> 4;
    const int a_oo = t >> 2, a_k4 = (t & 3) * 4;
    const int b_kk = t >> 4, b_e4 = (t & 15) * 4;
    float acc[4][4] = {{0.f}};
    for (int kd = 0; kd < 256; kd += 16) {
        const float4 wv = *reinterpret_cast<const float4*>(W + (o0 + a_oo) * Cc + kd + a_k4);
        const float4 av = *reinterpret_cast<const float4*>(Ac + ((long long)(b * Cc + kd + b_kk)) * Cc + e0 + b_e4);
        __syncthreads();
        As[a_k4 + 0][a_oo] = wv.x; As[a_k4 + 1][a_oo] = wv.y;
        As[a_k4 + 2][a_oo] = wv.z; As[a_k4 + 3][a_oo] = wv.w;
        *reinterpret_cast<float4*>(&Bs[b_kk][b_e4]) = av;
        __syncthreads();
#pragma unroll
        for (int kk = 0; kk < 16; ++kk) {
            const float4 a4 = *reinterpret_cast<const float4*>(&As[kk][ty * 4]);
            const float4 b4 = *reinterpret_cast<const float4*>(&Bs[kk][tx * 4]);
            const float aa[4] = {a4.x, a4.y, a4.z, a4.w};
            const float bb[4] = {b4.x, b4.y, b4.z, b4.w};
#pragma unroll
            for (int i = 0; i < 4; ++i)
#pragma unroll
                for (int j = 0; j < 4; ++j) acc[i][j] = fmaf(aa[i], bb[j], acc[i][j]);
        }
    }
#pragma unroll
    for (int i = 0; i < 4; ++i) {
        int2 pk;
        pk.x = (int)((unsigned)f2bf(acc[i][0]) | ((unsigned)f2bf(acc[i][1]) << 16));
        pk.y = (int)((unsigned)f2bf(acc[i][2]) | ((unsigned)f2bf(acc[i][3]) << 16));
        *reinterpret_cast<int2*>(WAb16 + ((long long)(b * Oo + o0 + ty * 4 + i)) * Cc + e0 + tx * 4) = pk;
    }
}

// ---------------- K7 v5: fused reprojection GEMM + bias + LN(512) + transposed store.
// All 16 A-fragments (K=256) preloaded up front (one HBM latency exposure);
// B (L2-resident) 1-step prefetch. grid (288, 1, 8), block 256 (4 waves x 128 o).
__global__ __launch_bounds__(256, 3) void k_rpln(const u16* __restrict__ Qexp,
                                                 const u16* __restrict__ WAb16,
                                                 const float* __restrict__ rbias,
                                                 const float* __restrict__ nw,
                                                 const float* __restrict__ nb,
                                                 float* __restrict__ out) {
    __shared__ float patch[4][16][36];          // per-wave 16 o x 32 n
    __shared__ float psum[32][4], psq[32][4];
    __shared__ float muA[32], rsA[32];

    const int t = threadIdx.x;
    const int b = blockIdx.z;
    const int n0 = blockIdx.x * 32;
    const int l = t & 63, w = t >> 6;           // wave w owns o = w*128..
    const int frow = l & 15, fk = (l >> 4) << 3;
    const int hi = l >> 4;

    f32x4 acc[2][8] = {};

    const u16* Aq = Qexp + ((long long)b * Nn + n0) * Cc;
    const u16* Bw = WAb16 + ((long long)b * Oo + w * 128) * Cc;

    // preload ALL A fragments: 2 n-halves x 8 K-steps
    int4 aF[2][8];
#pragma unroll
    for (int mi = 0; mi < 2; ++mi)
#pragma unroll
        for (int s = 0; s < 8; ++s)
            aF[mi][s] = *reinterpret_cast<const int4*>(Aq + (mi * 16 + frow) * Cc + s * 32 + fk);

    int4 bC[8], bN[8];
#pragma unroll
    for (int ni = 0; ni < 8; ++ni)
        bC[ni] = *reinterpret_cast<const int4*>(Bw + (ni * 16 + frow) * Cc + fk);

#pragma unroll
    for (int s = 0; s < 8; ++s) {
        if (s < 7) {
            const int kk = (s + 1) * 32 + fk;
#pragma unroll
            for (int ni = 0; ni < 8; ++ni)
                bN[ni] = *reinterpret_cast<const int4*>(Bw + (ni * 16 + frow) * Cc + kk);
        }
#pragma unroll
        for (int mi = 0; mi < 2; ++mi)
#pragma unroll
            for (int ni = 0; ni < 8; ++ni)
                acc[mi][ni] = __builtin_amdgcn_mfma_f32_16x16x32_bf16(
                    __builtin_bit_cast(short8, aF[mi][s]), __builtin_bit_cast(short8, bC[ni]),
                    acc[mi][ni], 0, 0, 0);
        if (s < 7) {
#pragma unroll
            for (int ni = 0; ni < 8; ++ni) bC[ni] = bN[ni];
        }
    }

    // ---- epilogue: +bias
#pragma unroll
    for (int ni = 0; ni < 8; ++ni) {
        const float bb = rbias[w * 128 + ni * 16 + frow];
#pragma unroll
        for (int mi = 0; mi < 2; ++mi)
#pragma unroll
            for (int r_ = 0; r_ < 4; ++r_) acc[mi][ni][r_] += bb;
    }
    // per-row LN partials over this wave's 128 cols
#pragma unroll
    for (int mi = 0; mi < 2; ++mi)
#pragma unroll
        for (int r_ = 0; r_ < 4; ++r_) {
            float s = 0.f, q = 0.f;
#pragma unroll
            for (int ni = 0; ni < 8; ++ni) { const float v = acc[mi][ni][r_]; s += v; q += v * v; }
#pragma unroll
            for (int m = 8; m; m >>= 1) { s += __shfl_xor(s, m); q += __shfl_xor(q, m); }
            if (frow == 0) {
                const int row = mi * 16 + hi * 4 + r_;
                psum[row][w] = s; psq[row][w] = q;
            }
        }
    __syncthreads();
    if (t < 32) {
        const float s = psum[t][0] + psum[t][1] + psum[t][2] + psum[t][3];
        const float q = psq[t][0] + psq[t][1] + psq[t][2] + psq[t][3];
        const float m = s * (1.0f / Oo);
        muA[t] = m;
        rsA[t] = rsqrtf(q * (1.0f / Oo) - m * m + LN_EPS);
    }
    __syncthreads();

    float nwv[8], nbv[8];
#pragma unroll
    for (int ni = 0; ni < 8; ++ni) {
        const int o = w * 128 + ni * 16 + frow;
        nwv[ni] = nw[o]; nbv[ni] = nb[o];
    }

    // per ni: wave-private 16o x 32n patch -> float4 stores (128-B segments).
#pragma unroll
    for (int ni = 0; ni < 8; ++ni) {
#pragma unroll
        for (int mi = 0; mi < 2; ++mi)
#pragma unroll
            for (int r_ = 0; r_ < 4; ++r_) {
                const int nl = mi * 16 + hi * 4 + r_;              // 0..31
                patch[w][frow][nl] = (acc[mi][ni][r_] - muA[nl]) * rsA[nl] * nwv[ni] + nbv[ni];
            }
        asm volatile("s_waitcnt lgkmcnt(0)" ::: "memory");
        __builtin_amdgcn_sched_barrier(0);
#pragma unroll
        for (int p = 0; p < 2; ++p) {
            const int o_loc = p * 8 + (l >> 3);                    // 0..15
            const int colf4 = l & 7;                               // 0..7
            const float4 v = *reinterpret_cast<const float4*>(&patch[w][o_loc][colf4 * 4]);
            const int o_g = w * 128 + ni * 16 + o_loc;
            *reinterpret_cast<float4*>(&out[((long long)(b * Oo + o_g)) * Nn + n0 + colf4 * 4]) = v;
        }
        asm volatile("s_waitcnt lgkmcnt(0)" ::: "memory");
        __builtin_amdgcn_sched_barrier(0);
    }
}

extern "C" void kernel_launch(void* const* d_in, const int* in_sizes, int n_in,
                              void* d_out, int out_size, void* d_ws, size_t ws_size,
                              hipStream_t stream) {
    (void)in_sizes; (void)n_in; (void)out_size; (void)ws_size;
    const float* x1    = (const float*)d_in[0];
    const float* x2    = (const float*)d_in[1];
    const float* n1w   = (const float*)d_in[2];
    const float* n1b   = (const float*)d_in[3];
    const float* rw    = (const float*)d_in[4];
    const float* rbias = (const float*)d_in[5];
    const float* n2w   = (const float*)d_in[6];
    const float* n2b   = (const float*)d_in[7];
    const float* aw    = (const float*)d_in[8];
    float* out = (float*)d_out;

    // d_out doubles as scratch for KexpT/VT (dead before k_rpln's final overwrite).
    u16* KexpT = (u16*)d_out;
    u16* VT    = KexpT + (size_t)Bb * Nn * Cc;

    float* ws = (float*)d_ws;
    size_t off = 0;
    u16*   Qexp   = (u16*)(ws + off); off += (size_t)Bb * Nn * Cc / 2;
    float* ctxp   = ws + off; off += (size_t)KS2 * Bb * Cc * Cc;
    float* ctx    = ws + off; off += (size_t)Bb * Cc * Cc;
    float* Ac     = ws + off; off += (size_t)Bb * Cc * Cc;
    u16*   WAb16  = (u16*)(ws + off); off += (size_t)Bb * Oo * Cc / 2;
    float* pS     = ws + off; off += (size_t)Bb * 144 * Cc;
    float* colS   = ws + off; off += (size_t)Bb * Cc;

    k_pre<<<dim3(144, 1, Bb), 512, 0, stream>>>(x2, n1w, n1b, KexpT, Qexp, pS, 1);
    k_pre<<<dim3(144, 1, Bb), 512, 0, stream>>>(x1, n1w, n1b, VT, Qexp, pS, 0);
    k_colcomb<<<dim3(Bb), 256, 0, stream>>>(pS, colS);
    k_mm_bf16<<<dim3(4, KS2, Bb), 256, 0, stream>>>(
        KexpT, VT, ctxp,
        Nn, Nn, Cc,
        (long long)Cc * Nn, (long long)Cc * Nn, (long long)Cc * Cc,
        Nn / KS2, (long long)Bb * Cc * Cc,
        Cc / 128, (Nn / KS2) / 64);
    k_ctxred<<<dim3(512), 256, 0, stream>>>(ctxp, colS, ctx);
    k_rank<<<dim3(Cc, Bb), 256, 0, stream>>>(ctx, aw, Ac);
    k_wa<<<dim3(32, Bb), 256, 0, stream>>>(rw, Ac, WAb16);
    k_rpln<<<dim3(288, 1, Bb), 256, 0, stream>>>(Qexp, WAb16, rbias, n2w, n2b, out);
}